// Round 8
// baseline (258.475 us; speedup 1.0000x reference)
//
#include <hip/hip_runtime.h>
#include <hip/hip_bf16.h>
#include <math.h>

#define N_NODES 50000
#define E_EDGES 800000
#define IN_DIM  128
#define HID     64
#define KF      4
#define EXP_HID 64

// d_out layout (float32, concatenated in return order):
//   disen_graph_emb (K*HID = 256) | Z (N*K*HID = 12,800,000) |
//   e_h_final (E = 800,000)       | e_h_all (K*E = 3,200,000)
#define OFF_DISEN 0
#define OFF_Z     (KF*HID)
#define OFF_EHF   (OFF_Z + N_NODES*KF*HID)
#define OFF_EHALL (OFF_EHF + E_EDGES)

#define NPB4 32                  // nodes per block (8 per wave)
#define NROWS (N_NODES * KF)     // 200000 (n,k) rows
#define PQ_ELEMS ((size_t)NROWS * EXP_HID)   // 12.8M elems each (bf16)
#define EPW 64                   // edges per wave in edge_kernel4

// ---------------------------------------------------------------------------
__global__ void disen_init_kernel(float* __restrict__ disen) {
  disen[threadIdx.x] = 0.f;
}

// ---------------------------------------------------------------------------
// Fused node-side kernel, v2. 1563 blocks x 256 threads, 32 nodes/block.
// Phase A (r5 z structure, acc[8][4]): Z = relu(x.W_init+b), row-normalize,
//   write Z, fold disen-max, park zn in LDS zt (aliased over x-stage).
// Phase B v2 (spill-free): LOOPS SWAPPED vs r7. Wave owns 32 rows with
//   accP[32]+accQ[32] in VGPRs (static index via full unroll); W1 streamed
//   in 8-h chunks of 16 regs (L1/L2-resident reloads). r7's ws[64]/wd[64]
//   needed 128 live regs across a rolled loop -> compiler spilled to
//   scratch at VGPR=84 (the 146us mystery). Live set now ~110 VGPR.
// ---------------------------------------------------------------------------
__global__ __launch_bounds__(256) void node_fused_kernel(
    const float* __restrict__ x, const float* __restrict__ W,
    const float* __restrict__ b, const float* __restrict__ W1,
    const float* __restrict__ b1, float* __restrict__ out,
    unsigned short* __restrict__ P, unsigned short* __restrict__ Q) {
  __shared__ __align__(16) float zt[NPB4 * KF * HID];  // 32 KB; rows (n*4+k)
  __shared__ float dred[4][KF][64];                    // 4 KB
  float* xs = zt;                                      // alias: phase A only
  const int tid = threadIdx.x;
  const int w = tid >> 6;
  const int lane = tid & 63;
  const int n0 = blockIdx.x * NPB4;

  // ---- phase A: stage 32 x-rows (clamped tail reads exact row N-1) ----
#pragma unroll
  for (int t = 0; t < 4; ++t) {
    const int idx = t * 256 + tid;
    const int row = idx >> 5;                          // 32 float4 per row
    const int col4 = idx & 31;
    const int nr = min(n0 + row, N_NODES - 1);
    ((float4*)xs)[idx] = ((const float4*)(x + (size_t)nr * IN_DIM))[col4];
  }
  __syncthreads();

  float acc[8][KF];
#pragma unroll
  for (int j = 0; j < 8; ++j)
#pragma unroll
    for (int k = 0; k < KF; ++k) acc[j][k] = b[k * HID + lane];

  const float* wp = W + lane;                          // W[k][i][h=lane]
#pragma unroll 2
  for (int i4 = 0; i4 < IN_DIM / 4; ++i4) {
    float wv[KF][4];
#pragma unroll
    for (int k = 0; k < KF; ++k)
#pragma unroll
      for (int i = 0; i < 4; ++i)
        wv[k][i] = wp[(k * IN_DIM + i4 * 4 + i) * HID];    // coalesced, L2
#pragma unroll
    for (int j = 0; j < 8; ++j) {
      const float4 xv = ((const float4*)(xs + (w * 8 + j) * IN_DIM))[i4];
#pragma unroll
      for (int k = 0; k < KF; ++k) {
        acc[j][k] = fmaf(xv.x, wv[k][0], acc[j][k]);
        acc[j][k] = fmaf(xv.y, wv[k][1], acc[j][k]);
        acc[j][k] = fmaf(xv.z, wv[k][2], acc[j][k]);
        acc[j][k] = fmaf(xv.w, wv[k][3], acc[j][k]);
      }
    }
  }
  __syncthreads();   // all waves done reading xs; zt overwrite is now safe

  // ---- normalize, write Z + zt, fold disen-max ----
  float dmax[KF];
#pragma unroll
  for (int k = 0; k < KF; ++k) dmax[k] = 0.f;

#pragma unroll
  for (int j = 0; j < 8; ++j) {
    const int node = n0 + w * 8 + j;
#pragma unroll
    for (int k = 0; k < KF; ++k) {
      float z = fmaxf(acc[j][k], 0.f);
      float s = z * z;
#pragma unroll
      for (int d = 1; d < 64; d <<= 1) s += __shfl_xor(s, d, 64);
      const float zn = z / fmaxf(sqrtf(s), 1e-12f);
      if (node < N_NODES)
        out[OFF_Z + (size_t)node * (KF * HID) + k * HID + lane] = zn;
      zt[((w * 8 + j) * KF + k) * HID + lane] = zn;    // row = n_in_blk*4+k
      dmax[k] = fmaxf(dmax[k], zn);   // clamped rows duplicate row N-1: ok
    }
  }
#pragma unroll
  for (int k = 0; k < KF; ++k) dred[w][k][lane] = dmax[k];
  __syncthreads();   // zt + dred ready

  {
    const int k = tid >> 6;
    const float m = fmaxf(fmaxf(dred[0][k][lane], dred[1][k][lane]),
                          fmaxf(dred[2][k][lane], dred[3][k][lane]));
    // Z >= 0: uint-punned atomicMax is exact & order-independent
    atomicMax((unsigned int*)(out + OFF_DISEN + tid), __float_as_uint(m));
  }

  // ---- phase B v2: P/Q from zt; acc-per-row, streamed weights ----
  float accP[32], accQ[32];                            // 64 VGPRs, static idx
#pragma unroll
  for (int r = 0; r < 32; ++r) { accP[r] = b1[lane]; accQ[r] = 0.f; }

  const float* ztw = zt + (w * 32) * HID;              // wave's 32 rows
  for (int hc = 0; hc < 8; ++hc) {                     // 8 h-chunks of 8
    float wsv[8], wdv[8];
#pragma unroll
    for (int j = 0; j < 8; ++j) {
      wsv[j] = W1[(hc * 8 + j) * EXP_HID + lane];      // coalesced, L1-hot
      wdv[j] = W1[(HID + hc * 8 + j) * EXP_HID + lane];
    }
#pragma unroll
    for (int r = 0; r < 32; ++r) {
      const float4 za = ((const float4*)(ztw + r * HID + hc * 8))[0];
      const float4 zb = ((const float4*)(ztw + r * HID + hc * 8))[1];
      accP[r] = fmaf(za.x, wsv[0], accP[r]);
      accQ[r] = fmaf(za.x, wdv[0], accQ[r]);
      accP[r] = fmaf(za.y, wsv[1], accP[r]);
      accQ[r] = fmaf(za.y, wdv[1], accQ[r]);
      accP[r] = fmaf(za.z, wsv[2], accP[r]);
      accQ[r] = fmaf(za.z, wdv[2], accQ[r]);
      accP[r] = fmaf(za.w, wsv[3], accP[r]);
      accQ[r] = fmaf(za.w, wdv[3], accQ[r]);
      accP[r] = fmaf(zb.x, wsv[4], accP[r]);
      accQ[r] = fmaf(zb.x, wdv[4], accQ[r]);
      accP[r] = fmaf(zb.y, wsv[5], accP[r]);
      accQ[r] = fmaf(zb.y, wdv[5], accQ[r]);
      accP[r] = fmaf(zb.z, wsv[6], accP[r]);
      accQ[r] = fmaf(zb.z, wdv[6], accQ[r]);
      accP[r] = fmaf(zb.w, wsv[7], accP[r]);
      accQ[r] = fmaf(zb.w, wdv[7], accQ[r]);
    }
  }

  const size_t growbase = (size_t)blockIdx.x * (NPB4 * KF) + w * 32;
#pragma unroll
  for (int r = 0; r < 32; ++r) {
    const size_t grow = growbase + r;
    if (grow < NROWS) {
      __hip_bfloat16 hp = __float2bfloat16(accP[r]);   // RNE
      __hip_bfloat16 hq = __float2bfloat16(accQ[r]);
      P[grow * EXP_HID + lane] = *(unsigned short*)&hp;
      Q[grow * EXP_HID + lane] = *(unsigned short*)&hq;
    }
  }
}

// ---------------------------------------------------------------------------
// Edge kernel (unchanged from r7): wave-cooperative gather, 64 edges/wave,
// padded LDS tile (k-stride 65) — r7 subtraction puts it at ~100-105us.
// ---------------------------------------------------------------------------
__global__ __launch_bounds__(256) void edge_kernel4(
    const int* __restrict__ ei, const float* __restrict__ W2,
    const float* __restrict__ b2, const unsigned short* __restrict__ P,
    const unsigned short* __restrict__ Q, float* __restrict__ ehf,
    float* __restrict__ ehall) {
  __shared__ float tile[4][KF][EPW + 1];           // pad: k-stride 65
  const int tid = threadIdx.x;
  const int w = tid >> 6;
  const int lane = tid & 63;
  const int eb = blockIdx.x * 256 + w * EPW;       // this wave's 64 edges

  const int o0 = (lane & 15) * 4;                  // lane's 4 output channels
  const float w2a = W2[o0 + 0], w2b = W2[o0 + 1];
  const float w2c = W2[o0 + 2], w2d = W2[o0 + 3];
  const float bias2 = b2[0];

  const int srcl = ei[eb + lane];                  // coalesced
  const int dstl = ei[E_EDGES + eb + lane];
  const int loff = lane * 4;                       // element offset in row

  uint2 pv[4], qv[4];
#pragma unroll
  for (int d = 0; d < 4; ++d) {
    const int s = __shfl(srcl, d, 64);             // readlane -> SGPR base
    const int t = __shfl(dstl, d, 64);
    pv[d] = *(const uint2*)(P + (size_t)s * (KF * EXP_HID) + loff);
    qv[d] = *(const uint2*)(Q + (size_t)t * (KF * EXP_HID) + loff);
  }

#pragma unroll
  for (int i = 0; i < EPW; ++i) {
    const uint2 p = pv[i & 3];
    const uint2 q = qv[i & 3];
    if (i + 4 < EPW) {                             // static under full unroll
      const int s = __shfl(srcl, i + 4, 64);
      const int t = __shfl(dstl, i + 4, 64);
      pv[i & 3] = *(const uint2*)(P + (size_t)s * (KF * EXP_HID) + loff);
      qv[i & 3] = *(const uint2*)(Q + (size_t)t * (KF * EXP_HID) + loff);
    }
    // unpack 4 bf16 pairs (exact bit-ops)
    const float pa = __uint_as_float(p.x << 16);
    const float pb = __uint_as_float(p.x & 0xffff0000u);
    const float pc = __uint_as_float(p.y << 16);
    const float pd = __uint_as_float(p.y & 0xffff0000u);
    const float qa = __uint_as_float(q.x << 16);
    const float qb = __uint_as_float(q.x & 0xffff0000u);
    const float qc = __uint_as_float(q.y << 16);
    const float qd = __uint_as_float(q.y & 0xffff0000u);

    float s4 = fmaxf(pa + qa, 0.f) * w2a;
    s4 = fmaf(fmaxf(pb + qb, 0.f), w2b, s4);
    s4 = fmaf(fmaxf(pc + qc, 0.f), w2c, s4);
    s4 = fmaf(fmaxf(pd + qd, 0.f), w2d, s4);

    // sum the 16 lanes of this k-group (masks < 16 stay in-group)
    s4 += __shfl_xor(s4, 1, 64);
    s4 += __shfl_xor(s4, 2, 64);
    s4 += __shfl_xor(s4, 4, 64);
    s4 += __shfl_xor(s4, 8, 64);
    if ((lane & 15) == 0) tile[w][lane >> 4][i] = s4 + bias2;
  }
  __syncthreads();

  const float v0 = tile[w][0][lane];
  const float v1 = tile[w][1][lane];
  const float v2 = tile[w][2][lane];
  const float v3 = tile[w][3][lane];
  ehall[(size_t)0 * E_EDGES + eb + lane] = v0;     // coalesced per wave
  ehall[(size_t)1 * E_EDGES + eb + lane] = v1;
  ehall[(size_t)2 * E_EDGES + eb + lane] = v2;
  ehall[(size_t)3 * E_EDGES + eb + lane] = v3;
  ehf[eb + lane] = fmaxf(fmaxf(v0, v1), fmaxf(v2, v3));
}

// ---------------------------------------------------------------------------
extern "C" void kernel_launch(void* const* d_in, const int* in_sizes, int n_in,
                              void* d_out, int out_size, void* d_ws,
                              size_t ws_size, hipStream_t stream) {
  const float* x      = (const float*)d_in[0];
  const int*   ei     = (const int*)  d_in[1];
  const float* W_init = (const float*)d_in[2];
  const float* b_init = (const float*)d_in[3];
  const float* W1     = (const float*)d_in[4];
  const float* b1     = (const float*)d_in[5];
  const float* W2     = (const float*)d_in[6];
  const float* b2     = (const float*)d_in[7];
  float* out = (float*)d_out;

  unsigned short* P = (unsigned short*)d_ws;     // ws >= 51.2MB (verified)
  unsigned short* Q = P + PQ_ELEMS;

  disen_init_kernel<<<1, KF * HID, 0, stream>>>(out + OFF_DISEN);
  node_fused_kernel<<<(N_NODES + NPB4 - 1) / NPB4, 256, 0, stream>>>(
      x, W_init, b_init, W1, b1, out, P, Q);
  edge_kernel4<<<E_EDGES / 256, 256, 0, stream>>>(
      ei, W2, b2, P, Q, out + OFF_EHF, out + OFF_EHALL);
}

// Round 9
// 257.715 us; speedup vs baseline: 1.0030x; 1.0030x over previous
//
#include <hip/hip_runtime.h>
#include <hip/hip_bf16.h>
#include <math.h>

#define N_NODES 50000
#define E_EDGES 800000
#define IN_DIM  128
#define HID     64
#define KF      4
#define EXP_HID 64

// d_out layout (float32, concatenated in return order):
//   disen_graph_emb (K*HID = 256) | Z (N*K*HID = 12,800,000) |
//   e_h_final (E = 800,000)       | e_h_all (K*E = 3,200,000)
#define OFF_DISEN 0
#define OFF_Z     (KF*HID)
#define OFF_EHF   (OFF_Z + N_NODES*KF*HID)
#define OFF_EHALL (OFF_EHF + E_EDGES)

#define NPB4 32                  // nodes per block (8 per wave)
#define NROWS (N_NODES * KF)     // 200000 (n,k) rows
#define PQ_ELEMS ((size_t)NROWS * EXP_HID)   // 12.8M elems each (bf16)
#define EPW 64                   // edges per wave in edge_kernel4

// ---------------------------------------------------------------------------
__global__ void disen_init_kernel(float* __restrict__ disen) {
  disen[threadIdx.x] = 0.f;
}

// ---------------------------------------------------------------------------
// Fused node-side kernel, v3. Identical to r8 EXCEPT __launch_bounds__(256,2).
// r7 (VGPR=84) and r8 (VGPR=60) both spilled phase-B state: the allocator's
// occupancy heuristic targeted 8 waves/SIMD (<=64 VGPR) although LDS (36.9KB)
// already caps the block at 4 blocks/CU — so the 64 accumulator registers
// went to AGPR/scratch round-trips (v_accvgpr moves = the VALUBusy excess).
// min-2-waves/EU raises the cap to 256; phase B needs ~110. Occupancy is
// LDS-limited either way -> no real occupancy loss.
// ---------------------------------------------------------------------------
__global__ __launch_bounds__(256, 2) void node_fused_kernel(
    const float* __restrict__ x, const float* __restrict__ W,
    const float* __restrict__ b, const float* __restrict__ W1,
    const float* __restrict__ b1, float* __restrict__ out,
    unsigned short* __restrict__ P, unsigned short* __restrict__ Q) {
  __shared__ __align__(16) float zt[NPB4 * KF * HID];  // 32 KB; rows (n*4+k)
  __shared__ float dred[4][KF][64];                    // 4 KB
  float* xs = zt;                                      // alias: phase A only
  const int tid = threadIdx.x;
  const int w = tid >> 6;
  const int lane = tid & 63;
  const int n0 = blockIdx.x * NPB4;

  // ---- phase A: stage 32 x-rows (clamped tail reads exact row N-1) ----
#pragma unroll
  for (int t = 0; t < 4; ++t) {
    const int idx = t * 256 + tid;
    const int row = idx >> 5;                          // 32 float4 per row
    const int col4 = idx & 31;
    const int nr = min(n0 + row, N_NODES - 1);
    ((float4*)xs)[idx] = ((const float4*)(x + (size_t)nr * IN_DIM))[col4];
  }
  __syncthreads();

  float acc[8][KF];
#pragma unroll
  for (int j = 0; j < 8; ++j)
#pragma unroll
    for (int k = 0; k < KF; ++k) acc[j][k] = b[k * HID + lane];

  const float* wp = W + lane;                          // W[k][i][h=lane]
#pragma unroll 2
  for (int i4 = 0; i4 < IN_DIM / 4; ++i4) {
    float wv[KF][4];
#pragma unroll
    for (int k = 0; k < KF; ++k)
#pragma unroll
      for (int i = 0; i < 4; ++i)
        wv[k][i] = wp[(k * IN_DIM + i4 * 4 + i) * HID];    // coalesced, L2
#pragma unroll
    for (int j = 0; j < 8; ++j) {
      const float4 xv = ((const float4*)(xs + (w * 8 + j) * IN_DIM))[i4];
#pragma unroll
      for (int k = 0; k < KF; ++k) {
        acc[j][k] = fmaf(xv.x, wv[k][0], acc[j][k]);
        acc[j][k] = fmaf(xv.y, wv[k][1], acc[j][k]);
        acc[j][k] = fmaf(xv.z, wv[k][2], acc[j][k]);
        acc[j][k] = fmaf(xv.w, wv[k][3], acc[j][k]);
      }
    }
  }
  __syncthreads();   // all waves done reading xs; zt overwrite is now safe

  // ---- normalize, write Z + zt, fold disen-max ----
  float dmax[KF];
#pragma unroll
  for (int k = 0; k < KF; ++k) dmax[k] = 0.f;

#pragma unroll
  for (int j = 0; j < 8; ++j) {
    const int node = n0 + w * 8 + j;
#pragma unroll
    for (int k = 0; k < KF; ++k) {
      float z = fmaxf(acc[j][k], 0.f);
      float s = z * z;
#pragma unroll
      for (int d = 1; d < 64; d <<= 1) s += __shfl_xor(s, d, 64);
      const float zn = z / fmaxf(sqrtf(s), 1e-12f);
      if (node < N_NODES)
        out[OFF_Z + (size_t)node * (KF * HID) + k * HID + lane] = zn;
      zt[((w * 8 + j) * KF + k) * HID + lane] = zn;    // row = n_in_blk*4+k
      dmax[k] = fmaxf(dmax[k], zn);   // clamped rows duplicate row N-1: ok
    }
  }
#pragma unroll
  for (int k = 0; k < KF; ++k) dred[w][k][lane] = dmax[k];
  __syncthreads();   // zt + dred ready

  {
    const int k = tid >> 6;
    const float m = fmaxf(fmaxf(dred[0][k][lane], dred[1][k][lane]),
                          fmaxf(dred[2][k][lane], dred[3][k][lane]));
    // Z >= 0: uint-punned atomicMax is exact & order-independent
    atomicMax((unsigned int*)(out + OFF_DISEN + tid), __float_as_uint(m));
  }

  // ---- phase B: P/Q from zt; acc-per-row, streamed weights ----
  float accP[32], accQ[32];                            // 64 VGPRs, static idx
#pragma unroll
  for (int r = 0; r < 32; ++r) { accP[r] = b1[lane]; accQ[r] = 0.f; }

  const float* ztw = zt + (w * 32) * HID;              // wave's 32 rows
  for (int hc = 0; hc < 8; ++hc) {                     // 8 h-chunks of 8
    float wsv[8], wdv[8];
#pragma unroll
    for (int j = 0; j < 8; ++j) {
      wsv[j] = W1[(hc * 8 + j) * EXP_HID + lane];      // coalesced, L1-hot
      wdv[j] = W1[(HID + hc * 8 + j) * EXP_HID + lane];
    }
#pragma unroll
    for (int r = 0; r < 32; ++r) {
      const float4 za = ((const float4*)(ztw + r * HID + hc * 8))[0];
      const float4 zb = ((const float4*)(ztw + r * HID + hc * 8))[1];
      accP[r] = fmaf(za.x, wsv[0], accP[r]);
      accQ[r] = fmaf(za.x, wdv[0], accQ[r]);
      accP[r] = fmaf(za.y, wsv[1], accP[r]);
      accQ[r] = fmaf(za.y, wdv[1], accQ[r]);
      accP[r] = fmaf(za.z, wsv[2], accP[r]);
      accQ[r] = fmaf(za.z, wdv[2], accQ[r]);
      accP[r] = fmaf(za.w, wsv[3], accP[r]);
      accQ[r] = fmaf(za.w, wdv[3], accQ[r]);
      accP[r] = fmaf(zb.x, wsv[4], accP[r]);
      accQ[r] = fmaf(zb.x, wdv[4], accQ[r]);
      accP[r] = fmaf(zb.y, wsv[5], accP[r]);
      accQ[r] = fmaf(zb.y, wdv[5], accQ[r]);
      accP[r] = fmaf(zb.z, wsv[6], accP[r]);
      accQ[r] = fmaf(zb.z, wdv[6], accQ[r]);
      accP[r] = fmaf(zb.w, wsv[7], accP[r]);
      accQ[r] = fmaf(zb.w, wdv[7], accQ[r]);
    }
  }

  const size_t growbase = (size_t)blockIdx.x * (NPB4 * KF) + w * 32;
#pragma unroll
  for (int r = 0; r < 32; ++r) {
    const size_t grow = growbase + r;
    if (grow < NROWS) {
      __hip_bfloat16 hp = __float2bfloat16(accP[r]);   // RNE
      __hip_bfloat16 hq = __float2bfloat16(accQ[r]);
      P[grow * EXP_HID + lane] = *(unsigned short*)&hp;
      Q[grow * EXP_HID + lane] = *(unsigned short*)&hq;
    }
  }
}

// ---------------------------------------------------------------------------
// Edge kernel (unchanged from r7): wave-cooperative gather, 64 edges/wave,
// padded LDS tile (k-stride 65).
// ---------------------------------------------------------------------------
__global__ __launch_bounds__(256) void edge_kernel4(
    const int* __restrict__ ei, const float* __restrict__ W2,
    const float* __restrict__ b2, const unsigned short* __restrict__ P,
    const unsigned short* __restrict__ Q, float* __restrict__ ehf,
    float* __restrict__ ehall) {
  __shared__ float tile[4][KF][EPW + 1];           // pad: k-stride 65
  const int tid = threadIdx.x;
  const int w = tid >> 6;
  const int lane = tid & 63;
  const int eb = blockIdx.x * 256 + w * EPW;       // this wave's 64 edges

  const int o0 = (lane & 15) * 4;                  // lane's 4 output channels
  const float w2a = W2[o0 + 0], w2b = W2[o0 + 1];
  const float w2c = W2[o0 + 2], w2d = W2[o0 + 3];
  const float bias2 = b2[0];

  const int srcl = ei[eb + lane];                  // coalesced
  const int dstl = ei[E_EDGES + eb + lane];
  const int loff = lane * 4;                       // element offset in row

  uint2 pv[4], qv[4];
#pragma unroll
  for (int d = 0; d < 4; ++d) {
    const int s = __shfl(srcl, d, 64);             // readlane -> SGPR base
    const int t = __shfl(dstl, d, 64);
    pv[d] = *(const uint2*)(P + (size_t)s * (KF * EXP_HID) + loff);
    qv[d] = *(const uint2*)(Q + (size_t)t * (KF * EXP_HID) + loff);
  }

#pragma unroll
  for (int i = 0; i < EPW; ++i) {
    const uint2 p = pv[i & 3];
    const uint2 q = qv[i & 3];
    if (i + 4 < EPW) {                             // static under full unroll
      const int s = __shfl(srcl, i + 4, 64);
      const int t = __shfl(dstl, i + 4, 64);
      pv[i & 3] = *(const uint2*)(P + (size_t)s * (KF * EXP_HID) + loff);
      qv[i & 3] = *(const uint2*)(Q + (size_t)t * (KF * EXP_HID) + loff);
    }
    // unpack 4 bf16 pairs (exact bit-ops)
    const float pa = __uint_as_float(p.x << 16);
    const float pb = __uint_as_float(p.x & 0xffff0000u);
    const float pc = __uint_as_float(p.y << 16);
    const float pd = __uint_as_float(p.y & 0xffff0000u);
    const float qa = __uint_as_float(q.x << 16);
    const float qb = __uint_as_float(q.x & 0xffff0000u);
    const float qc = __uint_as_float(q.y << 16);
    const float qd = __uint_as_float(q.y & 0xffff0000u);

    float s4 = fmaxf(pa + qa, 0.f) * w2a;
    s4 = fmaf(fmaxf(pb + qb, 0.f), w2b, s4);
    s4 = fmaf(fmaxf(pc + qc, 0.f), w2c, s4);
    s4 = fmaf(fmaxf(pd + qd, 0.f), w2d, s4);

    // sum the 16 lanes of this k-group (masks < 16 stay in-group)
    s4 += __shfl_xor(s4, 1, 64);
    s4 += __shfl_xor(s4, 2, 64);
    s4 += __shfl_xor(s4, 4, 64);
    s4 += __shfl_xor(s4, 8, 64);
    if ((lane & 15) == 0) tile[w][lane >> 4][i] = s4 + bias2;
  }
  __syncthreads();

  const float v0 = tile[w][0][lane];
  const float v1 = tile[w][1][lane];
  const float v2 = tile[w][2][lane];
  const float v3 = tile[w][3][lane];
  ehall[(size_t)0 * E_EDGES + eb + lane] = v0;     // coalesced per wave
  ehall[(size_t)1 * E_EDGES + eb + lane] = v1;
  ehall[(size_t)2 * E_EDGES + eb + lane] = v2;
  ehall[(size_t)3 * E_EDGES + eb + lane] = v3;
  ehf[eb + lane] = fmaxf(fmaxf(v0, v1), fmaxf(v2, v3));
}

// ---------------------------------------------------------------------------
extern "C" void kernel_launch(void* const* d_in, const int* in_sizes, int n_in,
                              void* d_out, int out_size, void* d_ws,
                              size_t ws_size, hipStream_t stream) {
  const float* x      = (const float*)d_in[0];
  const int*   ei     = (const int*)  d_in[1];
  const float* W_init = (const float*)d_in[2];
  const float* b_init = (const float*)d_in[3];
  const float* W1     = (const float*)d_in[4];
  const float* b1     = (const float*)d_in[5];
  const float* W2     = (const float*)d_in[6];
  const float* b2     = (const float*)d_in[7];
  float* out = (float*)d_out;

  unsigned short* P = (unsigned short*)d_ws;     // ws >= 51.2MB (verified)
  unsigned short* Q = P + PQ_ELEMS;

  disen_init_kernel<<<1, KF * HID, 0, stream>>>(out + OFF_DISEN);
  node_fused_kernel<<<(N_NODES + NPB4 - 1) / NPB4, 256, 0, stream>>>(
      x, W_init, b_init, W1, b1, out, P, Q);
  edge_kernel4<<<E_EDGES / 256, 256, 0, stream>>>(
      ei, W2, b2, P, Q, out + OFF_EHF, out + OFF_EHALL);
}

// Round 10
// 255.439 us; speedup vs baseline: 1.0119x; 1.0089x over previous
//
#include <hip/hip_runtime.h>
#include <hip/hip_bf16.h>
#include <math.h>

#define N_NODES 50000
#define E_EDGES 800000
#define IN_DIM  128
#define HID     64
#define KF      4
#define EXP_HID 64

// d_out layout (float32, concatenated in return order):
//   disen_graph_emb (K*HID = 256) | Z (N*K*HID = 12,800,000) |
//   e_h_final (E = 800,000)       | e_h_all (K*E = 3,200,000)
#define OFF_DISEN 0
#define OFF_Z     (KF*HID)
#define OFF_EHF   (OFF_Z + N_NODES*KF*HID)
#define OFF_EHALL (OFF_EHF + E_EDGES)

#define NPB3 32                  // nodes per block in z_kernel2 (8 per wave)
#define NROWS (N_NODES * KF)     // 200000 (n,k) rows
#define PQ_ELEMS ((size_t)NROWS * EXP_HID)   // 12.8M elems each (bf16)
#define EPW 64                   // edges per wave in edge_kernel4

// ---------------------------------------------------------------------------
__global__ void disen_init_kernel(float* __restrict__ disen) {
  disen[threadIdx.x] = 0.f;
}

// ---------------------------------------------------------------------------
// Kernel 1 (r5 verbatim): Z = relu(x.W_init+b), row-normalized, disen-max
// folded. Wave owns 8 nodes, lane = h, thread holds all 4 k (acc[8][4]).
// ---------------------------------------------------------------------------
__global__ __launch_bounds__(256) void z_kernel2(
    const float* __restrict__ x, const float* __restrict__ W,
    const float* __restrict__ b, float* __restrict__ out) {
  __shared__ __align__(16) float xs[NPB3 * IN_DIM];   // 16 KB
  __shared__ float dred[4][KF][64];                   // 4 KB
  const int tid = threadIdx.x;
  const int w = tid >> 6;
  const int lane = tid & 63;
  const int n0 = blockIdx.x * NPB3;

#pragma unroll
  for (int t = 0; t < 4; ++t) {
    const int idx = t * 256 + tid;
    const int row = idx >> 5;
    const int col4 = idx & 31;
    const int nr = min(n0 + row, N_NODES - 1);
    ((float4*)xs)[idx] = ((const float4*)(x + (size_t)nr * IN_DIM))[col4];
  }
  __syncthreads();

  float acc[8][KF];
#pragma unroll
  for (int j = 0; j < 8; ++j)
#pragma unroll
    for (int k = 0; k < KF; ++k) acc[j][k] = b[k * HID + lane];

  const float* wp = W + lane;
#pragma unroll 2
  for (int i4 = 0; i4 < IN_DIM / 4; ++i4) {
    float wv[KF][4];
#pragma unroll
    for (int k = 0; k < KF; ++k)
#pragma unroll
      for (int i = 0; i < 4; ++i)
        wv[k][i] = wp[(k * IN_DIM + i4 * 4 + i) * HID];
#pragma unroll
    for (int j = 0; j < 8; ++j) {
      const float4 xv = ((const float4*)(xs + (w * 8 + j) * IN_DIM))[i4];
#pragma unroll
      for (int k = 0; k < KF; ++k) {
        acc[j][k] = fmaf(xv.x, wv[k][0], acc[j][k]);
        acc[j][k] = fmaf(xv.y, wv[k][1], acc[j][k]);
        acc[j][k] = fmaf(xv.z, wv[k][2], acc[j][k]);
        acc[j][k] = fmaf(xv.w, wv[k][3], acc[j][k]);
      }
    }
  }

  float dmax[KF];
#pragma unroll
  for (int k = 0; k < KF; ++k) dmax[k] = 0.f;

#pragma unroll
  for (int j = 0; j < 8; ++j) {
    const int node = n0 + w * 8 + j;
#pragma unroll
    for (int k = 0; k < KF; ++k) {
      float z = fmaxf(acc[j][k], 0.f);
      float s = z * z;
#pragma unroll
      for (int d = 1; d < 64; d <<= 1) s += __shfl_xor(s, d, 64);
      const float zn = z / fmaxf(sqrtf(s), 1e-12f);
      if (node < N_NODES)
        out[OFF_Z + (size_t)node * (KF * HID) + k * HID + lane] = zn;
      dmax[k] = fmaxf(dmax[k], zn);
    }
  }

#pragma unroll
  for (int k = 0; k < KF; ++k) dred[w][k][lane] = dmax[k];
  __syncthreads();
  {
    const int k = tid >> 6;
    const float m = fmaxf(fmaxf(dred[0][k][lane], dred[1][k][lane]),
                          fmaxf(dred[2][k][lane], dred[3][k][lane]));
    // Z >= 0: uint-punned atomicMax is exact & order-independent
    atomicMax((unsigned int*)(out + OFF_DISEN + tid), __float_as_uint(m));
  }
}

// ---------------------------------------------------------------------------
// Kernel 2 (v2, spill-proof): P/Q bf16. 3125 blocks x 64 rows. Wave owns 16
// rows: accP[16]+accQ[16] (32 regs, static idx) + W1 streamed in 8-h chunks
// of 16 regs -> ~56 live VGPRs, fits the default 8-wave cap with no AGPR /
// scratch ambiguity (r7-r9 lesson). Same minimal LDS volume as r3 (16 b128
// broadcasts per row).
// ---------------------------------------------------------------------------
__global__ __launch_bounds__(256) void pq_kernel2(
    const float* __restrict__ Z, const float* __restrict__ W1,
    const float* __restrict__ b1, unsigned short* __restrict__ P,
    unsigned short* __restrict__ Q) {
  __shared__ __align__(16) float zt[64 * HID];         // 16 KB, 64 rows
  const int tid = threadIdx.x;
  const int lane = tid & 63;
  const int w = tid >> 6;
  const int base = blockIdx.x * 64;                    // 3125 * 64 = 200000

  // stage 64 rows (4096 floats) as 4x256 float4 loads
#pragma unroll
  for (int t = 0; t < 4; ++t)
    ((float4*)zt)[t * 256 + tid] =
        ((const float4*)(Z + (size_t)base * HID))[t * 256 + tid];
  __syncthreads();

  const float bb = b1[lane];
  float accP[16], accQ[16];
#pragma unroll
  for (int r = 0; r < 16; ++r) { accP[r] = bb; accQ[r] = 0.f; }

  const float* ztw = zt + (w * 16) * HID;              // wave's 16 rows
  for (int hc = 0; hc < 8; ++hc) {                     // 8 h-chunks of 8
    float wsv[8], wdv[8];
#pragma unroll
    for (int j = 0; j < 8; ++j) {
      wsv[j] = W1[(hc * 8 + j) * EXP_HID + lane];      // coalesced, L1-hot
      wdv[j] = W1[(HID + hc * 8 + j) * EXP_HID + lane];
    }
#pragma unroll
    for (int r = 0; r < 16; ++r) {
      const float4 za = ((const float4*)(ztw + r * HID + hc * 8))[0];
      const float4 zb = ((const float4*)(ztw + r * HID + hc * 8))[1];
      accP[r] = fmaf(za.x, wsv[0], accP[r]);
      accQ[r] = fmaf(za.x, wdv[0], accQ[r]);
      accP[r] = fmaf(za.y, wsv[1], accP[r]);
      accQ[r] = fmaf(za.y, wdv[1], accQ[r]);
      accP[r] = fmaf(za.z, wsv[2], accP[r]);
      accQ[r] = fmaf(za.z, wdv[2], accQ[r]);
      accP[r] = fmaf(za.w, wsv[3], accP[r]);
      accQ[r] = fmaf(za.w, wdv[3], accQ[r]);
      accP[r] = fmaf(zb.x, wsv[4], accP[r]);
      accQ[r] = fmaf(zb.x, wdv[4], accQ[r]);
      accP[r] = fmaf(zb.y, wsv[5], accP[r]);
      accQ[r] = fmaf(zb.y, wdv[5], accQ[r]);
      accP[r] = fmaf(zb.z, wsv[6], accP[r]);
      accQ[r] = fmaf(zb.z, wdv[6], accQ[r]);
      accP[r] = fmaf(zb.w, wsv[7], accP[r]);
      accQ[r] = fmaf(zb.w, wdv[7], accQ[r]);
    }
  }

  const size_t growbase = (size_t)base + w * 16;
#pragma unroll
  for (int r = 0; r < 16; ++r) {
    __hip_bfloat16 hp = __float2bfloat16(accP[r]);     // RNE
    __hip_bfloat16 hq = __float2bfloat16(accQ[r]);
    P[(growbase + r) * EXP_HID + lane] = *(unsigned short*)&hp;
    Q[(growbase + r) * EXP_HID + lane] = *(unsigned short*)&hq;
  }
}

// ---------------------------------------------------------------------------
// Kernel 3 (r7 verbatim): wave-cooperative gather, 64 edges/wave, padded
// LDS tile (k-stride 65).
// ---------------------------------------------------------------------------
__global__ __launch_bounds__(256) void edge_kernel4(
    const int* __restrict__ ei, const float* __restrict__ W2,
    const float* __restrict__ b2, const unsigned short* __restrict__ P,
    const unsigned short* __restrict__ Q, float* __restrict__ ehf,
    float* __restrict__ ehall) {
  __shared__ float tile[4][KF][EPW + 1];           // pad: k-stride 65
  const int tid = threadIdx.x;
  const int w = tid >> 6;
  const int lane = tid & 63;
  const int eb = blockIdx.x * 256 + w * EPW;       // this wave's 64 edges

  const int o0 = (lane & 15) * 4;                  // lane's 4 output channels
  const float w2a = W2[o0 + 0], w2b = W2[o0 + 1];
  const float w2c = W2[o0 + 2], w2d = W2[o0 + 3];
  const float bias2 = b2[0];

  const int srcl = ei[eb + lane];                  // coalesced
  const int dstl = ei[E_EDGES + eb + lane];
  const int loff = lane * 4;                       // element offset in row

  uint2 pv[4], qv[4];
#pragma unroll
  for (int d = 0; d < 4; ++d) {
    const int s = __shfl(srcl, d, 64);             // readlane -> SGPR base
    const int t = __shfl(dstl, d, 64);
    pv[d] = *(const uint2*)(P + (size_t)s * (KF * EXP_HID) + loff);
    qv[d] = *(const uint2*)(Q + (size_t)t * (KF * EXP_HID) + loff);
  }

#pragma unroll
  for (int i = 0; i < EPW; ++i) {
    const uint2 p = pv[i & 3];
    const uint2 q = qv[i & 3];
    if (i + 4 < EPW) {                             // static under full unroll
      const int s = __shfl(srcl, i + 4, 64);
      const int t = __shfl(dstl, i + 4, 64);
      pv[i & 3] = *(const uint2*)(P + (size_t)s * (KF * EXP_HID) + loff);
      qv[i & 3] = *(const uint2*)(Q + (size_t)t * (KF * EXP_HID) + loff);
    }
    // unpack 4 bf16 pairs (exact bit-ops)
    const float pa = __uint_as_float(p.x << 16);
    const float pb = __uint_as_float(p.x & 0xffff0000u);
    const float pc = __uint_as_float(p.y << 16);
    const float pd = __uint_as_float(p.y & 0xffff0000u);
    const float qa = __uint_as_float(q.x << 16);
    const float qb = __uint_as_float(q.x & 0xffff0000u);
    const float qc = __uint_as_float(q.y << 16);
    const float qd = __uint_as_float(q.y & 0xffff0000u);

    float s4 = fmaxf(pa + qa, 0.f) * w2a;
    s4 = fmaf(fmaxf(pb + qb, 0.f), w2b, s4);
    s4 = fmaf(fmaxf(pc + qc, 0.f), w2c, s4);
    s4 = fmaf(fmaxf(pd + qd, 0.f), w2d, s4);

    // sum the 16 lanes of this k-group (masks < 16 stay in-group)
    s4 += __shfl_xor(s4, 1, 64);
    s4 += __shfl_xor(s4, 2, 64);
    s4 += __shfl_xor(s4, 4, 64);
    s4 += __shfl_xor(s4, 8, 64);
    if ((lane & 15) == 0) tile[w][lane >> 4][i] = s4 + bias2;
  }
  __syncthreads();

  const float v0 = tile[w][0][lane];
  const float v1 = tile[w][1][lane];
  const float v2 = tile[w][2][lane];
  const float v3 = tile[w][3][lane];
  ehall[(size_t)0 * E_EDGES + eb + lane] = v0;     // coalesced per wave
  ehall[(size_t)1 * E_EDGES + eb + lane] = v1;
  ehall[(size_t)2 * E_EDGES + eb + lane] = v2;
  ehall[(size_t)3 * E_EDGES + eb + lane] = v3;
  ehf[eb + lane] = fmaxf(fmaxf(v0, v1), fmaxf(v2, v3));
}

// ---------------------------------------------------------------------------
extern "C" void kernel_launch(void* const* d_in, const int* in_sizes, int n_in,
                              void* d_out, int out_size, void* d_ws,
                              size_t ws_size, hipStream_t stream) {
  const float* x      = (const float*)d_in[0];
  const int*   ei     = (const int*)  d_in[1];
  const float* W_init = (const float*)d_in[2];
  const float* b_init = (const float*)d_in[3];
  const float* W1     = (const float*)d_in[4];
  const float* b1     = (const float*)d_in[5];
  const float* W2     = (const float*)d_in[6];
  const float* b2     = (const float*)d_in[7];
  float* out = (float*)d_out;

  unsigned short* P = (unsigned short*)d_ws;     // ws >= 51.2MB (verified)
  unsigned short* Q = P + PQ_ELEMS;

  disen_init_kernel<<<1, KF * HID, 0, stream>>>(out + OFF_DISEN);
  z_kernel2<<<(N_NODES + NPB3 - 1) / NPB3, 256, 0, stream>>>(
      x, W_init, b_init, out);
  pq_kernel2<<<NROWS / 64, 256, 0, stream>>>(out + OFF_Z, W1, b1, P, Q);
  edge_kernel4<<<E_EDGES / 256, 256, 0, stream>>>(
      ei, W2, b2, P, Q, out + OFF_EHF, out + OFF_EHALL);
}

// Round 11
// 206.677 us; speedup vs baseline: 1.2506x; 1.2359x over previous
//
#include <hip/hip_runtime.h>
#include <hip/hip_bf16.h>
#include <math.h>

#define N_NODES 50000
#define E_EDGES 800000
#define IN_DIM  128
#define HID     64
#define KF      4
#define EXP_HID 64

// d_out layout (float32, concatenated in return order):
//   disen_graph_emb (K*HID = 256) | Z (N*K*HID = 12,800,000) |
//   e_h_final (E = 800,000)       | e_h_all (K*E = 3,200,000)
#define OFF_DISEN 0
#define OFF_Z     (KF*HID)
#define OFF_EHF   (OFF_Z + N_NODES*KF*HID)
#define OFF_EHALL (OFF_EHF + E_EDGES)

#define NROWS (N_NODES * KF)     // 200000 (n,k) rows
#define PQ_ELEMS ((size_t)NROWS * EXP_HID)   // 12.8M elems each (bf16)
#define EPW 64                   // edges per wave in edge_kernel4

typedef __bf16 bf16x8 __attribute__((ext_vector_type(8)));
typedef float  f32x4  __attribute__((ext_vector_type(4)));
typedef unsigned short ushort_t;

// ---------------------------------------------------------------------------
__global__ void disen_init_kernel(float* __restrict__ disen) {
  disen[threadIdx.x] = 0.f;
}

// ---------------------------------------------------------------------------
// Weight pre-swizzle: pack W_init (z GEMM B, 128K x 256N) into per-fragment
// bf16 layout so each lane's MFMA B-frag is one contiguous 16B load:
//   elem (kk, col) -> Wz[((t*4+kh)*4+g)*128 + c*8 + e]
//   t=col>>4, c=col&15, kh=kk>>5, g=(kk>>3)&3, e=kk&7
// W_init[k][i][h]: B[kk=i][col=k*64+h].
// ---------------------------------------------------------------------------
__global__ void wfrag_z_kernel(const float* __restrict__ W,
                               __bf16* __restrict__ Wz) {
  const int tid = threadIdx.x;
  for (int i = 0; i < 128; ++i) {
    const int idx = i * 256 + tid;              // k*8192 + ii*64 + h
    const int k  = idx >> 13;
    const int ii = (idx >> 6) & 127;
    const int h  = idx & 63;
    const int col = k * 64 + h;
    const int t = col >> 4, c = col & 15;
    const int kh = ii >> 5, g = (ii >> 3) & 3, e = ii & 7;
    Wz[((t * 4 + kh) * 4 + g) * 128 + c * 8 + e] = (__bf16)W[idx];
  }
}

// pq GEMM B = [W1s | W1d] (64K x 128N): W1[r][cc] with r<64 -> (k=r, j=cc),
// r>=64 -> (k=r-64, j=64+cc). Frag layout as above with 2 k-halves.
__global__ void wfrag_pq_kernel(const float* __restrict__ W1,
                                __bf16* __restrict__ Wpq) {
  const int tid = threadIdx.x;
  for (int i = 0; i < 32; ++i) {
    const int idx = i * 256 + tid;              // r*64 + cc
    const int r = idx >> 6, cc = idx & 63;
    const int k = (r < 64) ? r : (r - 64);
    const int j = (r < 64) ? cc : (64 + cc);
    const int t = j >> 4, c = j & 15;
    const int kh = k >> 5, g = (k >> 3) & 3, e = k & 7;
    Wpq[((t * 2 + kh) * 4 + g) * 128 + c * 8 + e] = (__bf16)W1[idx];
  }
}

// ---------------------------------------------------------------------------
// z via MFMA: C(64n x 256(k,h)) = X(64x128) @ Wz per block; 4 waves, wave w
// owns 16 rows x all 16 N-tiles (64 MFMAs). Epilogue: +bias, relu, row-norm
// over h (in-lane + 16-lane shfl reduce), Z fp32 store, disen-max via LDS
// reduce + one atomicMax per (k,h) per block.
// ---------------------------------------------------------------------------
__global__ __launch_bounds__(256) void z_mfma_kernel(
    const float* __restrict__ x, const float* __restrict__ b_init,
    const __bf16* __restrict__ Wz, float* __restrict__ out) {
  __shared__ float dred[4][256];
  const int tid = threadIdx.x;
  const int w = tid >> 6, l = tid & 63;
  const int lg = l >> 4, lc = l & 15;
  const int n0 = blockIdx.x * 64;
  const int ra = min(n0 + w * 16 + lc, N_NODES - 1);   // A row (clamped tail)

  // A fragments: 4 K-halves of x[ra]
  bf16x8 af[4];
#pragma unroll
  for (int kh = 0; kh < 4; ++kh) {
    const float4* xp = (const float4*)(x + (size_t)ra * IN_DIM + kh * 32 + lg * 8);
    const float4 f0 = xp[0], f1 = xp[1];
    bf16x8 a;
    a[0] = (__bf16)f0.x; a[1] = (__bf16)f0.y;
    a[2] = (__bf16)f0.z; a[3] = (__bf16)f0.w;
    a[4] = (__bf16)f1.x; a[5] = (__bf16)f1.y;
    a[6] = (__bf16)f1.z; a[7] = (__bf16)f1.w;
    af[kh] = a;
  }

  f32x4 acc[16];
#pragma unroll
  for (int t = 0; t < 16; ++t) acc[t] = (f32x4){0.f, 0.f, 0.f, 0.f};

#pragma unroll
  for (int t = 0; t < 16; ++t)
#pragma unroll
    for (int kh = 0; kh < 4; ++kh) {
      const bf16x8 bf =
          *(const bf16x8*)(Wz + ((t * 4 + kh) * 4 + lg) * 128 + lc * 8);
      acc[t] = __builtin_amdgcn_mfma_f32_16x16x32_bf16(af[kh], bf, acc[t],
                                                       0, 0, 0);
    }

  // epilogue per k-factor: bias+relu, row-norm over 64 h (4 tiles x 16 lanes)
#pragma unroll
  for (int k = 0; k < KF; ++k) {
    float vals[4][4];
#pragma unroll
    for (int tt = 0; tt < 4; ++tt) {
      const int t = k * 4 + tt;
      const float bias = b_init[t * 16 + lc];
#pragma unroll
      for (int r = 0; r < 4; ++r)
        vals[tt][r] = fmaxf(acc[t][r] + bias, 0.f);
    }
    float s[4];
#pragma unroll
    for (int r = 0; r < 4; ++r)
      s[r] = vals[0][r] * vals[0][r] + vals[1][r] * vals[1][r] +
             vals[2][r] * vals[2][r] + vals[3][r] * vals[3][r];
#pragma unroll
    for (int d = 1; d < 16; d <<= 1)
#pragma unroll
      for (int r = 0; r < 4; ++r) s[r] += __shfl_xor(s[r], d, 64);
    float rn[4];
#pragma unroll
    for (int r = 0; r < 4; ++r)
      rn[r] = 1.f / fmaxf(sqrtf(s[r]), 1e-12f);

#pragma unroll
    for (int tt = 0; tt < 4; ++tt) {
      const int col = k * 64 + tt * 16 + lc;     // global (k,h) column
      float dmt = 0.f;
#pragma unroll
      for (int r = 0; r < 4; ++r) {
        const float zn = vals[tt][r] * rn[r];
        const int node = n0 + w * 16 + lg * 4 + r;
        if (node < N_NODES)
          out[OFF_Z + (size_t)node * (KF * HID) + col] = zn;
        dmt = fmaxf(dmt, zn);    // clamped dup rows repeat row N-1: harmless
      }
      dmt = fmaxf(dmt, __shfl_xor(dmt, 16, 64));
      dmt = fmaxf(dmt, __shfl_xor(dmt, 32, 64));
      if (lg == 0) dred[w][col] = dmt;
    }
  }
  __syncthreads();
  {
    const float m = fmaxf(fmaxf(dred[0][tid], dred[1][tid]),
                          fmaxf(dred[2][tid], dred[3][tid]));
    // Z >= 0: uint-punned atomicMax is exact & order-independent
    atomicMax((unsigned int*)(out + OFF_DISEN + tid), __float_as_uint(m));
  }
}

// ---------------------------------------------------------------------------
// pq via MFMA: [P|Q](200000 x 128) = Z(200000x64) @ Wpq. 3125 blocks x 64
// rows; wave owns 16 rows x 8 N-tiles (16 MFMAs, K=64 in 2 halves).
// Epilogue: +b1 on the P half, bf16 store.
// ---------------------------------------------------------------------------
__global__ __launch_bounds__(256) void pq_mfma_kernel(
    const float* __restrict__ Z, const float* __restrict__ b1,
    const __bf16* __restrict__ Wpq, ushort_t* __restrict__ P,
    ushort_t* __restrict__ Q) {
  const int tid = threadIdx.x;
  const int w = tid >> 6, l = tid & 63;
  const int lg = l >> 4, lc = l & 15;
  const int base = blockIdx.x * 64;              // exact: 3125*64 = 200000
  const int rowA = base + w * 16 + lc;

  bf16x8 af[2];
#pragma unroll
  for (int kh = 0; kh < 2; ++kh) {
    const float4* zp = (const float4*)(Z + (size_t)rowA * HID + kh * 32 + lg * 8);
    const float4 f0 = zp[0], f1 = zp[1];
    bf16x8 a;
    a[0] = (__bf16)f0.x; a[1] = (__bf16)f0.y;
    a[2] = (__bf16)f0.z; a[3] = (__bf16)f0.w;
    a[4] = (__bf16)f1.x; a[5] = (__bf16)f1.y;
    a[6] = (__bf16)f1.z; a[7] = (__bf16)f1.w;
    af[kh] = a;
  }

  f32x4 acc[8];
#pragma unroll
  for (int t = 0; t < 8; ++t) acc[t] = (f32x4){0.f, 0.f, 0.f, 0.f};

#pragma unroll
  for (int t = 0; t < 8; ++t)
#pragma unroll
    for (int kh = 0; kh < 2; ++kh) {
      const bf16x8 bf =
          *(const bf16x8*)(Wpq + ((t * 2 + kh) * 4 + lg) * 128 + lc * 8);
      acc[t] = __builtin_amdgcn_mfma_f32_16x16x32_bf16(af[kh], bf, acc[t],
                                                       0, 0, 0);
    }

#pragma unroll
  for (int t = 0; t < 8; ++t) {
    const int j = t * 16 + lc;                   // 0..127
    const float bias = (t < 4) ? b1[j] : 0.f;
    ushort_t* const dst = (t < 4) ? P : Q;
    const int o = (t < 4) ? j : (j - 64);
#pragma unroll
    for (int r = 0; r < 4; ++r) {
      const int grow = base + w * 16 + lg * 4 + r;
      const float v = acc[t][r] + bias;
      __hip_bfloat16 hb = __float2bfloat16(v);   // RNE
      dst[(size_t)grow * EXP_HID + o] = *(ushort_t*)&hb;
    }
  }
}

// ---------------------------------------------------------------------------
// Edge kernel (r7/r10 verbatim): wave-cooperative gather, 64 edges/wave,
// padded LDS tile (k-stride 65). Measured ~113us, at the L3 scatter rate.
// ---------------------------------------------------------------------------
__global__ __launch_bounds__(256) void edge_kernel4(
    const int* __restrict__ ei, const float* __restrict__ W2,
    const float* __restrict__ b2, const ushort_t* __restrict__ P,
    const ushort_t* __restrict__ Q, float* __restrict__ ehf,
    float* __restrict__ ehall) {
  __shared__ float tile[4][KF][EPW + 1];           // pad: k-stride 65
  const int tid = threadIdx.x;
  const int w = tid >> 6;
  const int lane = tid & 63;
  const int eb = blockIdx.x * 256 + w * EPW;       // this wave's 64 edges

  const int o0 = (lane & 15) * 4;                  // lane's 4 output channels
  const float w2a = W2[o0 + 0], w2b = W2[o0 + 1];
  const float w2c = W2[o0 + 2], w2d = W2[o0 + 3];
  const float bias2 = b2[0];

  const int srcl = ei[eb + lane];                  // coalesced
  const int dstl = ei[E_EDGES + eb + lane];
  const int loff = lane * 4;                       // element offset in row

  uint2 pv[4], qv[4];
#pragma unroll
  for (int d = 0; d < 4; ++d) {
    const int s = __shfl(srcl, d, 64);             // readlane -> SGPR base
    const int t = __shfl(dstl, d, 64);
    pv[d] = *(const uint2*)(P + (size_t)s * (KF * EXP_HID) + loff);
    qv[d] = *(const uint2*)(Q + (size_t)t * (KF * EXP_HID) + loff);
  }

#pragma unroll
  for (int i = 0; i < EPW; ++i) {
    const uint2 p = pv[i & 3];
    const uint2 q = qv[i & 3];
    if (i + 4 < EPW) {                             // static under full unroll
      const int s = __shfl(srcl, i + 4, 64);
      const int t = __shfl(dstl, i + 4, 64);
      pv[i & 3] = *(const uint2*)(P + (size_t)s * (KF * EXP_HID) + loff);
      qv[i & 3] = *(const uint2*)(Q + (size_t)t * (KF * EXP_HID) + loff);
    }
    // unpack 4 bf16 pairs (exact bit-ops)
    const float pa = __uint_as_float(p.x << 16);
    const float pb = __uint_as_float(p.x & 0xffff0000u);
    const float pc = __uint_as_float(p.y << 16);
    const float pd = __uint_as_float(p.y & 0xffff0000u);
    const float qa = __uint_as_float(q.x << 16);
    const float qb = __uint_as_float(q.x & 0xffff0000u);
    const float qc = __uint_as_float(q.y << 16);
    const float qd = __uint_as_float(q.y & 0xffff0000u);

    float s4 = fmaxf(pa + qa, 0.f) * w2a;
    s4 = fmaf(fmaxf(pb + qb, 0.f), w2b, s4);
    s4 = fmaf(fmaxf(pc + qc, 0.f), w2c, s4);
    s4 = fmaf(fmaxf(pd + qd, 0.f), w2d, s4);

    // sum the 16 lanes of this k-group (masks < 16 stay in-group)
    s4 += __shfl_xor(s4, 1, 64);
    s4 += __shfl_xor(s4, 2, 64);
    s4 += __shfl_xor(s4, 4, 64);
    s4 += __shfl_xor(s4, 8, 64);
    if ((lane & 15) == 0) tile[w][lane >> 4][i] = s4 + bias2;
  }
  __syncthreads();

  const float v0 = tile[w][0][lane];
  const float v1 = tile[w][1][lane];
  const float v2 = tile[w][2][lane];
  const float v3 = tile[w][3][lane];
  ehall[(size_t)0 * E_EDGES + eb + lane] = v0;     // coalesced per wave
  ehall[(size_t)1 * E_EDGES + eb + lane] = v1;
  ehall[(size_t)2 * E_EDGES + eb + lane] = v2;
  ehall[(size_t)3 * E_EDGES + eb + lane] = v3;
  ehf[eb + lane] = fmaxf(fmaxf(v0, v1), fmaxf(v2, v3));
}

// ---------------------------------------------------------------------------
extern "C" void kernel_launch(void* const* d_in, const int* in_sizes, int n_in,
                              void* d_out, int out_size, void* d_ws,
                              size_t ws_size, hipStream_t stream) {
  const float* x      = (const float*)d_in[0];
  const int*   ei     = (const int*)  d_in[1];
  const float* W_init = (const float*)d_in[2];
  const float* b_init = (const float*)d_in[3];
  const float* W1     = (const float*)d_in[4];
  const float* b1     = (const float*)d_in[5];
  const float* W2     = (const float*)d_in[6];
  const float* b2     = (const float*)d_in[7];
  float* out = (float*)d_out;

  // d_ws: P (25.6MB) | Q (25.6MB) | Wz (64KB) | Wpq (16KB). ws>=102MB (r2).
  ushort_t* P = (ushort_t*)d_ws;
  ushort_t* Q = P + PQ_ELEMS;
  __bf16* Wz  = (__bf16*)(Q + PQ_ELEMS);
  __bf16* Wpq = Wz + 32768;

  disen_init_kernel<<<1, KF * HID, 0, stream>>>(out + OFF_DISEN);
  wfrag_z_kernel<<<1, 256, 0, stream>>>(W_init, Wz);
  wfrag_pq_kernel<<<1, 256, 0, stream>>>(W1, Wpq);
  z_mfma_kernel<<<(N_NODES + 63) / 64, 256, 0, stream>>>(
      x, b_init, Wz, out);
  pq_mfma_kernel<<<NROWS / 64, 256, 0, stream>>>(
      out + OFF_Z, b1, Wpq, P, Q);
  edge_kernel4<<<E_EDGES / 256, 256, 0, stream>>>(
      ei, W2, b2, P, Q, out + OFF_EHF, out + OFF_EHALL);
}

// Round 12
// 197.423 us; speedup vs baseline: 1.3092x; 1.0469x over previous
//
#include <hip/hip_runtime.h>
#include <hip/hip_bf16.h>
#include <math.h>

#define N_NODES 50000
#define E_EDGES 800000
#define IN_DIM  128
#define HID     64
#define KF      4
#define EXP_HID 64

// d_out layout (float32, concatenated in return order):
//   disen_graph_emb (K*HID = 256) | Z (N*K*HID = 12,800,000) |
//   e_h_final (E = 800,000)       | e_h_all (K*E = 3,200,000)
#define OFF_DISEN 0
#define OFF_Z     (KF*HID)
#define OFF_EHF   (OFF_Z + N_NODES*KF*HID)
#define OFF_EHALL (OFF_EHF + E_EDGES)

#define NROWS (N_NODES * KF)     // 200000 (n,k) rows
#define PQ_ELEMS ((size_t)NROWS * EXP_HID)   // 12.8M elems each (bf16)
#define EPW 64                   // edges per wave in edge_kernel4

typedef __bf16 bf16x8 __attribute__((ext_vector_type(8)));
typedef float  f32x4  __attribute__((ext_vector_type(4)));
typedef unsigned short ushort_t;

// ---------------------------------------------------------------------------
// prep: one kernel, 41 blocks. Blocks 0-31: Wz fragment swizzle (32768
// elems); 32-39: Wpq swizzle (8192 elems); 40: disen init. r11 ran the
// swizzles as single-block kernels = 1 CU serial (~15-25us) — now parallel.
// ---------------------------------------------------------------------------
__global__ __launch_bounds__(256) void prep_kernel(
    const float* __restrict__ W, const float* __restrict__ W1,
    float* __restrict__ disen, __bf16* __restrict__ Wz,
    __bf16* __restrict__ Wpq) {
  const int b = blockIdx.x, tid = threadIdx.x;
  if (b < 32) {
#pragma unroll
    for (int i = 0; i < 4; ++i) {
      const int idx = (b * 4 + i) * 256 + tid;    // k*8192 + ii*64 + h
      const int k  = idx >> 13;
      const int ii = (idx >> 6) & 127;
      const int h  = idx & 63;
      const int col = k * 64 + h;
      const int t = col >> 4, c = col & 15;
      const int kh = ii >> 5, g = (ii >> 3) & 3, e = ii & 7;
      Wz[((t * 4 + kh) * 4 + g) * 128 + c * 8 + e] = (__bf16)W[idx];
    }
  } else if (b < 40) {
#pragma unroll
    for (int i = 0; i < 4; ++i) {
      const int idx = ((b - 32) * 4 + i) * 256 + tid;   // r*64 + cc
      const int r = idx >> 6, cc = idx & 63;
      const int k = (r < 64) ? r : (r - 64);
      const int j = (r < 64) ? cc : (64 + cc);
      const int t = j >> 4, c = j & 15;
      const int kh = k >> 5, g = (k >> 3) & 3, e = k & 7;
      Wpq[((t * 2 + kh) * 4 + g) * 128 + c * 8 + e] = (__bf16)W1[idx];
    }
  } else {
    disen[tid] = 0.f;
  }
}

// ---------------------------------------------------------------------------
// Fused node MFMA kernel. 782 blocks x 256 threads, 64 nodes/block.
// Phase A (r11 z_mfma): C(64n x 256(k,h)) = X @ Wz; epilogue does
//   bias+relu+row-norm, fp32 Z store, disen-max, AND parks bf16(zn) in a
//   swizzled LDS tile ztb (256 rows x 128B).
// Phase B (r11 pq_mfma off LDS): [P|Q] = Zt @ Wpq, 4 iters x 16 rows/wave,
//   A-frags via single ds_read_b128 each. Kills the 51MB Z global re-read.
// Swizzle sc = chunk ^ (row&7) ^ ((row>>3)&6): phase-A 64-lane writes land
//   8 distinct 16B chunks (lcH^2*lg injective) -> <=2 lanes/bank (free);
//   phase-B reads permute over lc&7 -> 2-way (free). Same formula both
//   sides (rule 21).
// ---------------------------------------------------------------------------
__global__ __launch_bounds__(256) void node_mfma_kernel(
    const float* __restrict__ x, const float* __restrict__ b_init,
    const float* __restrict__ b1, const __bf16* __restrict__ Wz,
    const __bf16* __restrict__ Wpq, float* __restrict__ out,
    ushort_t* __restrict__ P, ushort_t* __restrict__ Q) {
  __shared__ __align__(16) unsigned char ztb[256 * 128];  // 32 KB bf16 tile
  __shared__ float dred[4][256];                          // 4 KB
  const int tid = threadIdx.x;
  const int w = tid >> 6, l = tid & 63;
  const int lg = l >> 4, lc = l & 15;
  const int n0 = blockIdx.x * 64;
  const int ra = min(n0 + w * 16 + lc, N_NODES - 1);   // A row (clamped tail)

  // ---- phase A: A-fragments (4 K-halves of x[ra]) ----
  bf16x8 af[4];
#pragma unroll
  for (int kh = 0; kh < 4; ++kh) {
    const float4* xp = (const float4*)(x + (size_t)ra * IN_DIM + kh * 32 + lg * 8);
    const float4 f0 = xp[0], f1 = xp[1];
    bf16x8 a;
    a[0] = (__bf16)f0.x; a[1] = (__bf16)f0.y;
    a[2] = (__bf16)f0.z; a[3] = (__bf16)f0.w;
    a[4] = (__bf16)f1.x; a[5] = (__bf16)f1.y;
    a[6] = (__bf16)f1.z; a[7] = (__bf16)f1.w;
    af[kh] = a;
  }

  f32x4 acc[16];
#pragma unroll
  for (int t = 0; t < 16; ++t) acc[t] = (f32x4){0.f, 0.f, 0.f, 0.f};

#pragma unroll
  for (int t = 0; t < 16; ++t)
#pragma unroll
    for (int kh = 0; kh < 4; ++kh) {
      const bf16x8 bf =
          *(const bf16x8*)(Wz + ((t * 4 + kh) * 4 + lg) * 128 + lc * 8);
      acc[t] = __builtin_amdgcn_mfma_f32_16x16x32_bf16(af[kh], bf, acc[t],
                                                       0, 0, 0);
    }

  // ---- epilogue: bias+relu, row-norm, Z store (fp32) + ztb store (bf16) ----
#pragma unroll
  for (int k = 0; k < KF; ++k) {
    float vals[4][4];
#pragma unroll
    for (int tt = 0; tt < 4; ++tt) {
      const int t = k * 4 + tt;
      const float bias = b_init[t * 16 + lc];
#pragma unroll
      for (int r = 0; r < 4; ++r)
        vals[tt][r] = fmaxf(acc[t][r] + bias, 0.f);
    }
    float s[4];
#pragma unroll
    for (int r = 0; r < 4; ++r)
      s[r] = vals[0][r] * vals[0][r] + vals[1][r] * vals[1][r] +
             vals[2][r] * vals[2][r] + vals[3][r] * vals[3][r];
#pragma unroll
    for (int d = 1; d < 16; d <<= 1)
#pragma unroll
      for (int r = 0; r < 4; ++r) s[r] += __shfl_xor(s[r], d, 64);
    float rn[4];
#pragma unroll
    for (int r = 0; r < 4; ++r)
      rn[r] = 1.f / fmaxf(sqrtf(s[r]), 1e-12f);

#pragma unroll
    for (int tt = 0; tt < 4; ++tt) {
      const int col = k * 64 + tt * 16 + lc;     // global (k,h) column
      float dmt = 0.f;
#pragma unroll
      for (int r = 0; r < 4; ++r) {
        const float zn = vals[tt][r] * rn[r];
        const int node = n0 + w * 16 + lg * 4 + r;
        if (node < N_NODES)
          out[OFF_Z + (size_t)node * (KF * HID) + col] = zn;
        // swizzled LDS store of bf16(zn) (identical value phase B consumed
        // via global in r11 -> absmax unchanged)
        const int row = (w * 16 + lg * 4 + r) * 4 + k;
        const int chunk = tt * 2 + (lc >> 3);
        const int sc = chunk ^ (row & 7) ^ ((row >> 3) & 6);
        __hip_bfloat16 hz = __float2bfloat16(zn);
        *(ushort_t*)(ztb + row * 128 + sc * 16 + (lc & 7) * 2) =
            *(ushort_t*)&hz;
        dmt = fmaxf(dmt, zn);    // clamped dup rows repeat row N-1: harmless
      }
      dmt = fmaxf(dmt, __shfl_xor(dmt, 16, 64));
      dmt = fmaxf(dmt, __shfl_xor(dmt, 32, 64));
      if (lg == 0) dred[w][col] = dmt;
    }
  }
  __syncthreads();   // ztb + dred ready

  {
    const float m = fmaxf(fmaxf(dred[0][tid], dred[1][tid]),
                          fmaxf(dred[2][tid], dred[3][tid]));
    // Z >= 0: uint-punned atomicMax is exact & order-independent
    atomicMax((unsigned int*)(out + OFF_DISEN + tid), __float_as_uint(m));
  }

  // ---- phase B: [P|Q] = Zt @ Wpq, 4 iters x 16 rows per wave ----
  float biasv[4];
#pragma unroll
  for (int t = 0; t < 4; ++t) biasv[t] = b1[t * 16 + lc];

#pragma unroll
  for (int it = 0; it < 4; ++it) {
    const int rLA = w * 64 + it * 16 + lc;       // A row for this lane
    bf16x8 paf[2];
#pragma unroll
    for (int kh = 0; kh < 2; ++kh) {
      const int sc = (kh * 4 + lg) ^ (rLA & 7) ^ ((rLA >> 3) & 6);
      paf[kh] = *(const bf16x8*)(ztb + rLA * 128 + sc * 16);
    }

    f32x4 pacc[8];
#pragma unroll
    for (int t = 0; t < 8; ++t) pacc[t] = (f32x4){0.f, 0.f, 0.f, 0.f};
#pragma unroll
    for (int t = 0; t < 8; ++t)
#pragma unroll
      for (int kh = 0; kh < 2; ++kh) {
        const bf16x8 bf =
            *(const bf16x8*)(Wpq + ((t * 2 + kh) * 4 + lg) * 128 + lc * 8);
        pacc[t] = __builtin_amdgcn_mfma_f32_16x16x32_bf16(paf[kh], bf,
                                                          pacc[t], 0, 0, 0);
      }

#pragma unroll
    for (int t = 0; t < 8; ++t) {
      const int j = t * 16 + lc;                 // 0..127
      const float bias = (t < 4) ? biasv[t] : 0.f;
      ushort_t* const dst = (t < 4) ? P : Q;
      const int o = (t < 4) ? j : (j - 64);
#pragma unroll
      for (int r = 0; r < 4; ++r) {
        const size_t grow = (size_t)n0 * KF + w * 64 + it * 16 + lg * 4 + r;
        if (grow < NROWS) {
          const float v = pacc[t][r] + bias;
          __hip_bfloat16 hb = __float2bfloat16(v);   // RNE
          dst[grow * EXP_HID + o] = *(ushort_t*)&hb;
        }
      }
    }
  }
}

// ---------------------------------------------------------------------------
// Edge kernel (r7/r10 verbatim): wave-cooperative gather, 64 edges/wave,
// padded LDS tile (k-stride 65). Measured ~113-116us, at the L3 scatter
// rate (~3.4 TB/s on 372MB) across three structural variants.
// ---------------------------------------------------------------------------
__global__ __launch_bounds__(256) void edge_kernel4(
    const int* __restrict__ ei, const float* __restrict__ W2,
    const float* __restrict__ b2, const ushort_t* __restrict__ P,
    const ushort_t* __restrict__ Q, float* __restrict__ ehf,
    float* __restrict__ ehall) {
  __shared__ float tile[4][KF][EPW + 1];           // pad: k-stride 65
  const int tid = threadIdx.x;
  const int w = tid >> 6;
  const int lane = tid & 63;
  const int eb = blockIdx.x * 256 + w * EPW;       // this wave's 64 edges

  const int o0 = (lane & 15) * 4;                  // lane's 4 output channels
  const float w2a = W2[o0 + 0], w2b = W2[o0 + 1];
  const float w2c = W2[o0 + 2], w2d = W2[o0 + 3];
  const float bias2 = b2[0];

  const int srcl = ei[eb + lane];                  // coalesced
  const int dstl = ei[E_EDGES + eb + lane];
  const int loff = lane * 4;                       // element offset in row

  uint2 pv[4], qv[4];
#pragma unroll
  for (int d = 0; d < 4; ++d) {
    const int s = __shfl(srcl, d, 64);             // readlane -> SGPR base
    const int t = __shfl(dstl, d, 64);
    pv[d] = *(const uint2*)(P + (size_t)s * (KF * EXP_HID) + loff);
    qv[d] = *(const uint2*)(Q + (size_t)t * (KF * EXP_HID) + loff);
  }

#pragma unroll
  for (int i = 0; i < EPW; ++i) {
    const uint2 p = pv[i & 3];
    const uint2 q = qv[i & 3];
    if (i + 4 < EPW) {                             // static under full unroll
      const int s = __shfl(srcl, i + 4, 64);
      const int t = __shfl(dstl, i + 4, 64);
      pv[i & 3] = *(const uint2*)(P + (size_t)s * (KF * EXP_HID) + loff);
      qv[i & 3] = *(const uint2*)(Q + (size_t)t * (KF * EXP_HID) + loff);
    }
    // unpack 4 bf16 pairs (exact bit-ops)
    const float pa = __uint_as_float(p.x << 16);
    const float pb = __uint_as_float(p.x & 0xffff0000u);
    const float pc = __uint_as_float(p.y << 16);
    const float pd = __uint_as_float(p.y & 0xffff0000u);
    const float qa = __uint_as_float(q.x << 16);
    const float qb = __uint_as_float(q.x & 0xffff0000u);
    const float qc = __uint_as_float(q.y << 16);
    const float qd = __uint_as_float(q.y & 0xffff0000u);

    float s4 = fmaxf(pa + qa, 0.f) * w2a;
    s4 = fmaf(fmaxf(pb + qb, 0.f), w2b, s4);
    s4 = fmaf(fmaxf(pc + qc, 0.f), w2c, s4);
    s4 = fmaf(fmaxf(pd + qd, 0.f), w2d, s4);

    // sum the 16 lanes of this k-group (masks < 16 stay in-group)
    s4 += __shfl_xor(s4, 1, 64);
    s4 += __shfl_xor(s4, 2, 64);
    s4 += __shfl_xor(s4, 4, 64);
    s4 += __shfl_xor(s4, 8, 64);
    if ((lane & 15) == 0) tile[w][lane >> 4][i] = s4 + bias2;
  }
  __syncthreads();

  const float v0 = tile[w][0][lane];
  const float v1 = tile[w][1][lane];
  const float v2 = tile[w][2][lane];
  const float v3 = tile[w][3][lane];
  ehall[(size_t)0 * E_EDGES + eb + lane] = v0;     // coalesced per wave
  ehall[(size_t)1 * E_EDGES + eb + lane] = v1;
  ehall[(size_t)2 * E_EDGES + eb + lane] = v2;
  ehall[(size_t)3 * E_EDGES + eb + lane] = v3;
  ehf[eb + lane] = fmaxf(fmaxf(v0, v1), fmaxf(v2, v3));
}

// ---------------------------------------------------------------------------
extern "C" void kernel_launch(void* const* d_in, const int* in_sizes, int n_in,
                              void* d_out, int out_size, void* d_ws,
                              size_t ws_size, hipStream_t stream) {
  const float* x      = (const float*)d_in[0];
  const int*   ei     = (const int*)  d_in[1];
  const float* W_init = (const float*)d_in[2];
  const float* b_init = (const float*)d_in[3];
  const float* W1     = (const float*)d_in[4];
  const float* b1     = (const float*)d_in[5];
  const float* W2     = (const float*)d_in[6];
  const float* b2     = (const float*)d_in[7];
  float* out = (float*)d_out;

  // d_ws: P (25.6MB) | Q (25.6MB) | Wz (64KB) | Wpq (16KB). ws>=102MB (r2).
  ushort_t* P = (ushort_t*)d_ws;
  ushort_t* Q = P + PQ_ELEMS;
  __bf16* Wz  = (__bf16*)(Q + PQ_ELEMS);
  __bf16* Wpq = Wz + 32768;

  prep_kernel<<<41, 256, 0, stream>>>(W_init, W1, out + OFF_DISEN, Wz, Wpq);
  node_mfma_kernel<<<(N_NODES + 63) / 64, 256, 0, stream>>>(
      x, b_init, b1, Wz, Wpq, out, P, Q);
  edge_kernel4<<<E_EDGES / 256, 256, 0, stream>>>(
      ei, W2, b2, P, Q, out + OFF_EHF, out + OFF_EHALL);
}

// Round 13
// 176.286 us; speedup vs baseline: 1.4662x; 1.1199x over previous
//
#include <hip/hip_runtime.h>
#include <hip/hip_bf16.h>
#include <math.h>

#define N_NODES 50000
#define E_EDGES 800000
#define IN_DIM  128
#define HID     64
#define KF      4
#define EXP_HID 64

// d_out layout (float32, concatenated in return order):
//   disen_graph_emb (K*HID = 256) | Z (N*K*HID = 12,800,000) |
//   e_h_final (E = 800,000)       | e_h_all (K*E = 3,200,000)
#define OFF_DISEN 0
#define OFF_Z     (KF*HID)
#define OFF_EHF   (OFF_Z + N_NODES*KF*HID)
#define OFF_EHALL (OFF_EHF + E_EDGES)

#define NROWS (N_NODES * KF)     // 200000 (n,k) rows
#define PQ_ELEMS ((size_t)NROWS * EXP_HID)   // 12.8M elems each (bf16)
#define EPW 64                   // edges per wave in edge_kernel4

typedef __bf16 bf16x8 __attribute__((ext_vector_type(8)));
typedef float  f32x4  __attribute__((ext_vector_type(4)));
typedef unsigned short ushort_t;

// ---------------------------------------------------------------------------
// prep (r12 verbatim): 41 blocks. 0-31: Wz swizzle; 32-39: Wpq swizzle;
// 40: disen init.
// ---------------------------------------------------------------------------
__global__ __launch_bounds__(256) void prep_kernel(
    const float* __restrict__ W, const float* __restrict__ W1,
    float* __restrict__ disen, __bf16* __restrict__ Wz,
    __bf16* __restrict__ Wpq) {
  const int b = blockIdx.x, tid = threadIdx.x;
  if (b < 32) {
#pragma unroll
    for (int i = 0; i < 4; ++i) {
      const int idx = (b * 4 + i) * 256 + tid;    // k*8192 + ii*64 + h
      const int k  = idx >> 13;
      const int ii = (idx >> 6) & 127;
      const int h  = idx & 63;
      const int col = k * 64 + h;
      const int t = col >> 4, c = col & 15;
      const int kh = ii >> 5, g = (ii >> 3) & 3, e = ii & 7;
      Wz[((t * 4 + kh) * 4 + g) * 128 + c * 8 + e] = (__bf16)W[idx];
    }
  } else if (b < 40) {
#pragma unroll
    for (int i = 0; i < 4; ++i) {
      const int idx = ((b - 32) * 4 + i) * 256 + tid;   // r*64 + cc
      const int r = idx >> 6, cc = idx & 63;
      const int k = (r < 64) ? r : (r - 64);
      const int j = (r < 64) ? cc : (64 + cc);
      const int t = j >> 4, c = j & 15;
      const int kh = k >> 5, g = (k >> 3) & 3, e = k & 7;
      Wpq[((t * 2 + kh) * 4 + g) * 128 + c * 8 + e] = (__bf16)W1[idx];
    }
  } else {
    disen[tid] = 0.f;
  }
}

// ---------------------------------------------------------------------------
// z via MFMA, v2 (k-phased): per k-factor, only 4 f32x4 accumulators live
// (16 VGPR vs 64 in r11/r12) -> target <=70 VGPR, LDS just dred (4KB) ->
// occupancy up to 8 waves/SIMD vs the fused kernel's 4. #pragma unroll 1
// keeps the phase live-ranges disjoint (r7/r8 spill lesson). Arithmetic
// identical to r12 -> absmax unchanged.
// ---------------------------------------------------------------------------
__global__ __launch_bounds__(256) void z_mfma_kernel2(
    const float* __restrict__ x, const float* __restrict__ b_init,
    const __bf16* __restrict__ Wz, float* __restrict__ out) {
  __shared__ float dred[4][256];
  const int tid = threadIdx.x;
  const int w = tid >> 6, l = tid & 63;
  const int lg = l >> 4, lc = l & 15;
  const int n0 = blockIdx.x * 64;
  const int ra = min(n0 + w * 16 + lc, N_NODES - 1);   // A row (clamped tail)

  // A fragments: 4 K-halves of x[ra] (live across all k phases)
  bf16x8 af[4];
#pragma unroll
  for (int kh = 0; kh < 4; ++kh) {
    const float4* xp = (const float4*)(x + (size_t)ra * IN_DIM + kh * 32 + lg * 8);
    const float4 f0 = xp[0], f1 = xp[1];
    bf16x8 a;
    a[0] = (__bf16)f0.x; a[1] = (__bf16)f0.y;
    a[2] = (__bf16)f0.z; a[3] = (__bf16)f0.w;
    a[4] = (__bf16)f1.x; a[5] = (__bf16)f1.y;
    a[6] = (__bf16)f1.z; a[7] = (__bf16)f1.w;
    af[kh] = a;
  }

#pragma unroll 1
  for (int k = 0; k < KF; ++k) {
    f32x4 acc[4];
#pragma unroll
    for (int tt = 0; tt < 4; ++tt) acc[tt] = (f32x4){0.f, 0.f, 0.f, 0.f};

#pragma unroll
    for (int tt = 0; tt < 4; ++tt)
#pragma unroll
      for (int kh = 0; kh < 4; ++kh) {
        const bf16x8 bf = *(const bf16x8*)(
            Wz + (((k * 4 + tt) * 4 + kh) * 4 + lg) * 128 + lc * 8);
        acc[tt] = __builtin_amdgcn_mfma_f32_16x16x32_bf16(af[kh], bf, acc[tt],
                                                          0, 0, 0);
      }

    // epilogue for this k: bias+relu, row-norm over 64 h, Z store, disen-max
    float vals[4][4];
#pragma unroll
    for (int tt = 0; tt < 4; ++tt) {
      const float bias = b_init[(k * 4 + tt) * 16 + lc];
#pragma unroll
      for (int r = 0; r < 4; ++r)
        vals[tt][r] = fmaxf(acc[tt][r] + bias, 0.f);
    }
    float s[4];
#pragma unroll
    for (int r = 0; r < 4; ++r)
      s[r] = vals[0][r] * vals[0][r] + vals[1][r] * vals[1][r] +
             vals[2][r] * vals[2][r] + vals[3][r] * vals[3][r];
#pragma unroll
    for (int d = 1; d < 16; d <<= 1)
#pragma unroll
      for (int r = 0; r < 4; ++r) s[r] += __shfl_xor(s[r], d, 64);
    float rn[4];
#pragma unroll
    for (int r = 0; r < 4; ++r)
      rn[r] = 1.f / fmaxf(sqrtf(s[r]), 1e-12f);

#pragma unroll
    for (int tt = 0; tt < 4; ++tt) {
      const int col = k * 64 + tt * 16 + lc;     // global (k,h) column
      float dmt = 0.f;
#pragma unroll
      for (int r = 0; r < 4; ++r) {
        const float zn = vals[tt][r] * rn[r];
        const int node = n0 + w * 16 + lg * 4 + r;
        if (node < N_NODES)
          out[OFF_Z + (size_t)node * (KF * HID) + col] = zn;
        dmt = fmaxf(dmt, zn);    // clamped dup rows repeat row N-1: harmless
      }
      dmt = fmaxf(dmt, __shfl_xor(dmt, 16, 64));
      dmt = fmaxf(dmt, __shfl_xor(dmt, 32, 64));
      if (lg == 0) dred[w][col] = dmt;
    }
  }
  __syncthreads();
  {
    const float m = fmaxf(fmaxf(dred[0][tid], dred[1][tid]),
                          fmaxf(dred[2][tid], dred[3][tid]));
    // Z >= 0: uint-punned atomicMax is exact & order-independent
    atomicMax((unsigned int*)(out + OFF_DISEN + tid), __float_as_uint(m));
  }
}

// ---------------------------------------------------------------------------
// pq via MFMA (r11 verbatim — measured-good, zero LDS, ~64 VGPR):
// [P|Q](200000 x 128) = Z @ Wpq; 3125 blocks x 64 rows; wave owns 16 rows
// x 8 N-tiles. Z read from d_out (L3-resident, just written).
// ---------------------------------------------------------------------------
__global__ __launch_bounds__(256) void pq_mfma_kernel(
    const float* __restrict__ Z, const float* __restrict__ b1,
    const __bf16* __restrict__ Wpq, ushort_t* __restrict__ P,
    ushort_t* __restrict__ Q) {
  const int tid = threadIdx.x;
  const int w = tid >> 6, l = tid & 63;
  const int lg = l >> 4, lc = l & 15;
  const int base = blockIdx.x * 64;              // exact: 3125*64 = 200000
  const int rowA = base + w * 16 + lc;

  bf16x8 af[2];
#pragma unroll
  for (int kh = 0; kh < 2; ++kh) {
    const float4* zp = (const float4*)(Z + (size_t)rowA * HID + kh * 32 + lg * 8);
    const float4 f0 = zp[0], f1 = zp[1];
    bf16x8 a;
    a[0] = (__bf16)f0.x; a[1] = (__bf16)f0.y;
    a[2] = (__bf16)f0.z; a[3] = (__bf16)f0.w;
    a[4] = (__bf16)f1.x; a[5] = (__bf16)f1.y;
    a[6] = (__bf16)f1.z; a[7] = (__bf16)f1.w;
    af[kh] = a;
  }

  f32x4 acc[8];
#pragma unroll
  for (int t = 0; t < 8; ++t) acc[t] = (f32x4){0.f, 0.f, 0.f, 0.f};

#pragma unroll
  for (int t = 0; t < 8; ++t)
#pragma unroll
    for (int kh = 0; kh < 2; ++kh) {
      const bf16x8 bf =
          *(const bf16x8*)(Wpq + ((t * 2 + kh) * 4 + lg) * 128 + lc * 8);
      acc[t] = __builtin_amdgcn_mfma_f32_16x16x32_bf16(af[kh], bf, acc[t],
                                                       0, 0, 0);
    }

#pragma unroll
  for (int t = 0; t < 8; ++t) {
    const int j = t * 16 + lc;                   // 0..127
    const float bias = (t < 4) ? b1[j] : 0.f;
    ushort_t* const dst = (t < 4) ? P : Q;
    const int o = (t < 4) ? j : (j - 64);
#pragma unroll
    for (int r = 0; r < 4; ++r) {
      const int grow = base + w * 16 + lg * 4 + r;
      const float v = acc[t][r] + bias;
      __hip_bfloat16 hb = __float2bfloat16(v);   // RNE
      dst[(size_t)grow * EXP_HID + o] = *(ushort_t*)&hb;
    }
  }
}

// ---------------------------------------------------------------------------
// Edge kernel (unchanged since r7): wave-cooperative gather, 64 edges/wave,
// padded LDS tile. Measured 113-116us across rounds — L2-miss path at
// ~3.4 TB/s on 372MB.
// ---------------------------------------------------------------------------
__global__ __launch_bounds__(256) void edge_kernel4(
    const int* __restrict__ ei, const float* __restrict__ W2,
    const float* __restrict__ b2, const ushort_t* __restrict__ P,
    const ushort_t* __restrict__ Q, float* __restrict__ ehf,
    float* __restrict__ ehall) {
  __shared__ float tile[4][KF][EPW + 1];           // pad: k-stride 65
  const int tid = threadIdx.x;
  const int w = tid >> 6;
  const int lane = tid & 63;
  const int eb = blockIdx.x * 256 + w * EPW;       // this wave's 64 edges

  const int o0 = (lane & 15) * 4;                  // lane's 4 output channels
  const float w2a = W2[o0 + 0], w2b = W2[o0 + 1];
  const float w2c = W2[o0 + 2], w2d = W2[o0 + 3];
  const float bias2 = b2[0];

  const int srcl = ei[eb + lane];                  // coalesced
  const int dstl = ei[E_EDGES + eb + lane];
  const int loff = lane * 4;                       // element offset in row

  uint2 pv[4], qv[4];
#pragma unroll
  for (int d = 0; d < 4; ++d) {
    const int s = __shfl(srcl, d, 64);             // readlane -> SGPR base
    const int t = __shfl(dstl, d, 64);
    pv[d] = *(const uint2*)(P + (size_t)s * (KF * EXP_HID) + loff);
    qv[d] = *(const uint2*)(Q + (size_t)t * (KF * EXP_HID) + loff);
  }

#pragma unroll
  for (int i = 0; i < EPW; ++i) {
    const uint2 p = pv[i & 3];
    const uint2 q = qv[i & 3];
    if (i + 4 < EPW) {                             // static under full unroll
      const int s = __shfl(srcl, i + 4, 64);
      const int t = __shfl(dstl, i + 4, 64);
      pv[i & 3] = *(const uint2*)(P + (size_t)s * (KF * EXP_HID) + loff);
      qv[i & 3] = *(const uint2*)(Q + (size_t)t * (KF * EXP_HID) + loff);
    }
    // unpack 4 bf16 pairs (exact bit-ops)
    const float pa = __uint_as_float(p.x << 16);
    const float pb = __uint_as_float(p.x & 0xffff0000u);
    const float pc = __uint_as_float(p.y << 16);
    const float pd = __uint_as_float(p.y & 0xffff0000u);
    const float qa = __uint_as_float(q.x << 16);
    const float qb = __uint_as_float(q.x & 0xffff0000u);
    const float qc = __uint_as_float(q.y << 16);
    const float qd = __uint_as_float(q.y & 0xffff0000u);

    float s4 = fmaxf(pa + qa, 0.f) * w2a;
    s4 = fmaf(fmaxf(pb + qb, 0.f), w2b, s4);
    s4 = fmaf(fmaxf(pc + qc, 0.f), w2c, s4);
    s4 = fmaf(fmaxf(pd + qd, 0.f), w2d, s4);

    // sum the 16 lanes of this k-group (masks < 16 stay in-group)
    s4 += __shfl_xor(s4, 1, 64);
    s4 += __shfl_xor(s4, 2, 64);
    s4 += __shfl_xor(s4, 4, 64);
    s4 += __shfl_xor(s4, 8, 64);
    if ((lane & 15) == 0) tile[w][lane >> 4][i] = s4 + bias2;
  }
  __syncthreads();

  const float v0 = tile[w][0][lane];
  const float v1 = tile[w][1][lane];
  const float v2 = tile[w][2][lane];
  const float v3 = tile[w][3][lane];
  ehall[(size_t)0 * E_EDGES + eb + lane] = v0;     // coalesced per wave
  ehall[(size_t)1 * E_EDGES + eb + lane] = v1;
  ehall[(size_t)2 * E_EDGES + eb + lane] = v2;
  ehall[(size_t)3 * E_EDGES + eb + lane] = v3;
  ehf[eb + lane] = fmaxf(fmaxf(v0, v1), fmaxf(v2, v3));
}

// ---------------------------------------------------------------------------
extern "C" void kernel_launch(void* const* d_in, const int* in_sizes, int n_in,
                              void* d_out, int out_size, void* d_ws,
                              size_t ws_size, hipStream_t stream) {
  const float* x      = (const float*)d_in[0];
  const int*   ei     = (const int*)  d_in[1];
  const float* W_init = (const float*)d_in[2];
  const float* b_init = (const float*)d_in[3];
  const float* W1     = (const float*)d_in[4];
  const float* b1     = (const float*)d_in[5];
  const float* W2     = (const float*)d_in[6];
  const float* b2     = (const float*)d_in[7];
  float* out = (float*)d_out;

  // d_ws: P (25.6MB) | Q (25.6MB) | Wz (64KB) | Wpq (16KB). ws>=102MB (r2).
  ushort_t* P = (ushort_t*)d_ws;
  ushort_t* Q = P + PQ_ELEMS;
  __bf16* Wz  = (__bf16*)(Q + PQ_ELEMS);
  __bf16* Wpq = Wz + 32768;

  prep_kernel<<<41, 256, 0, stream>>>(W_init, W1, out + OFF_DISEN, Wz, Wpq);
  z_mfma_kernel2<<<(N_NODES + 63) / 64, 256, 0, stream>>>(
      x, b_init, Wz, out);
  pq_mfma_kernel<<<NROWS / 64, 256, 0, stream>>>(
      out + OFF_Z, b1, Wpq, P, Q);
  edge_kernel4<<<E_EDGES / 256, 256, 0, stream>>>(
      ei, W2, b2, P, Q, out + OFF_EHF, out + OFF_EHALL);
}

// Round 14
// 132.948 us; speedup vs baseline: 1.9442x; 1.3260x over previous
//
#include <hip/hip_runtime.h>
#include <hip/hip_bf16.h>
#include <math.h>

#define N_NODES 50000
#define E_EDGES 800000
#define IN_DIM  128
#define HID     64
#define KF      4
#define EXP_HID 64

// d_out layout (float32, concatenated in return order):
//   disen_graph_emb (K*HID = 256) | Z (N*K*HID = 12,800,000) |
//   e_h_final (E = 800,000)       | e_h_all (K*E = 3,200,000)
#define OFF_DISEN 0
#define OFF_Z     (KF*HID)
#define OFF_EHF   (OFF_Z + N_NODES*KF*HID)
#define OFF_EHALL (OFF_EHF + E_EDGES)

#define NROWS (N_NODES * KF)     // 200000 (n,k) rows
#define EPW 64                   // edges per wave in edge_kernel5

typedef __bf16 bf16x8 __attribute__((ext_vector_type(8)));
typedef float  f32x4  __attribute__((ext_vector_type(4)));
typedef unsigned short ushort_t;
typedef unsigned int   uint_t;

// ---------------------------------------------------------------------------
// prep (r12 verbatim): 41 blocks. 0-31: Wz swizzle; 32-39: Wpq swizzle;
// 40: disen init.
// ---------------------------------------------------------------------------
__global__ __launch_bounds__(256) void prep_kernel(
    const float* __restrict__ W, const float* __restrict__ W1,
    float* __restrict__ disen, __bf16* __restrict__ Wz,
    __bf16* __restrict__ Wpq) {
  const int b = blockIdx.x, tid = threadIdx.x;
  if (b < 32) {
#pragma unroll
    for (int i = 0; i < 4; ++i) {
      const int idx = (b * 4 + i) * 256 + tid;    // k*8192 + ii*64 + h
      const int k  = idx >> 13;
      const int ii = (idx >> 6) & 127;
      const int h  = idx & 63;
      const int col = k * 64 + h;
      const int t = col >> 4, c = col & 15;
      const int kh = ii >> 5, g = (ii >> 3) & 3, e = ii & 7;
      Wz[((t * 4 + kh) * 4 + g) * 128 + c * 8 + e] = (__bf16)W[idx];
    }
  } else if (b < 40) {
#pragma unroll
    for (int i = 0; i < 4; ++i) {
      const int idx = ((b - 32) * 4 + i) * 256 + tid;   // r*64 + cc
      const int r = idx >> 6, cc = idx & 63;
      const int k = (r < 64) ? r : (r - 64);
      const int j = (r < 64) ? cc : (64 + cc);
      const int t = j >> 4, c = j & 15;
      const int kh = k >> 5, g = (k >> 3) & 3, e = k & 7;
      Wpq[((t * 2 + kh) * 4 + g) * 128 + c * 8 + e] = (__bf16)W1[idx];
    }
  } else {
    disen[tid] = 0.f;
  }
}

// ---------------------------------------------------------------------------
// z via MFMA (r13 verbatim, k-phased). Measured-good.
// ---------------------------------------------------------------------------
__global__ __launch_bounds__(256) void z_mfma_kernel2(
    const float* __restrict__ x, const float* __restrict__ b_init,
    const __bf16* __restrict__ Wz, float* __restrict__ out) {
  __shared__ float dred[4][256];
  const int tid = threadIdx.x;
  const int w = tid >> 6, l = tid & 63;
  const int lg = l >> 4, lc = l & 15;
  const int n0 = blockIdx.x * 64;
  const int ra = min(n0 + w * 16 + lc, N_NODES - 1);   // A row (clamped tail)

  bf16x8 af[4];
#pragma unroll
  for (int kh = 0; kh < 4; ++kh) {
    const float4* xp = (const float4*)(x + (size_t)ra * IN_DIM + kh * 32 + lg * 8);
    const float4 f0 = xp[0], f1 = xp[1];
    bf16x8 a;
    a[0] = (__bf16)f0.x; a[1] = (__bf16)f0.y;
    a[2] = (__bf16)f0.z; a[3] = (__bf16)f0.w;
    a[4] = (__bf16)f1.x; a[5] = (__bf16)f1.y;
    a[6] = (__bf16)f1.z; a[7] = (__bf16)f1.w;
    af[kh] = a;
  }

#pragma unroll 1
  for (int k = 0; k < KF; ++k) {
    f32x4 acc[4];
#pragma unroll
    for (int tt = 0; tt < 4; ++tt) acc[tt] = (f32x4){0.f, 0.f, 0.f, 0.f};

#pragma unroll
    for (int tt = 0; tt < 4; ++tt)
#pragma unroll
      for (int kh = 0; kh < 4; ++kh) {
        const bf16x8 bf = *(const bf16x8*)(
            Wz + (((k * 4 + tt) * 4 + kh) * 4 + lg) * 128 + lc * 8);
        acc[tt] = __builtin_amdgcn_mfma_f32_16x16x32_bf16(af[kh], bf, acc[tt],
                                                          0, 0, 0);
      }

    float vals[4][4];
#pragma unroll
    for (int tt = 0; tt < 4; ++tt) {
      const float bias = b_init[(k * 4 + tt) * 16 + lc];
#pragma unroll
      for (int r = 0; r < 4; ++r)
        vals[tt][r] = fmaxf(acc[tt][r] + bias, 0.f);
    }
    float s[4];
#pragma unroll
    for (int r = 0; r < 4; ++r)
      s[r] = vals[0][r] * vals[0][r] + vals[1][r] * vals[1][r] +
             vals[2][r] * vals[2][r] + vals[3][r] * vals[3][r];
#pragma unroll
    for (int d = 1; d < 16; d <<= 1)
#pragma unroll
      for (int r = 0; r < 4; ++r) s[r] += __shfl_xor(s[r], d, 64);
    float rn[4];
#pragma unroll
    for (int r = 0; r < 4; ++r)
      rn[r] = 1.f / fmaxf(sqrtf(s[r]), 1e-12f);

#pragma unroll
    for (int tt = 0; tt < 4; ++tt) {
      const int col = k * 64 + tt * 16 + lc;
      float dmt = 0.f;
#pragma unroll
      for (int r = 0; r < 4; ++r) {
        const float zn = vals[tt][r] * rn[r];
        const int node = n0 + w * 16 + lg * 4 + r;
        if (node < N_NODES)
          out[OFF_Z + (size_t)node * (KF * HID) + col] = zn;
        dmt = fmaxf(dmt, zn);
      }
      dmt = fmaxf(dmt, __shfl_xor(dmt, 16, 64));
      dmt = fmaxf(dmt, __shfl_xor(dmt, 32, 64));
      if (lg == 0) dred[w][col] = dmt;
    }
  }
  __syncthreads();
  {
    const float m = fmaxf(fmaxf(dred[0][tid], dred[1][tid]),
                          fmaxf(dred[2][tid], dred[3][tid]));
    atomicMax((unsigned int*)(out + OFF_DISEN + tid), __float_as_uint(m));
  }
}

// ---------------------------------------------------------------------------
// pq via MFMA -> int8 P/Q with per-row scales.
// MFMA part = r11 verbatim. Epilogue: per output row (n,k): rowmax of |P|
// and |Q| (16-lane shfl reduce), quantize q = rint(v*127/max), pack the
// lane's 4 fragment values (orig cols {t*16+lc}) into ONE dword stored at
// row byte lc*4 -> row layout byte[lc*4+t] = col[t*16+lc] (a fixed
// permutation; edge dot is order-invariant as long as W2 coefs match).
// Row = exactly one 64B line; scales in Psc/Qsc[grow].
// ---------------------------------------------------------------------------
__global__ __launch_bounds__(256) void pq_mfma_kernel2(
    const float* __restrict__ Z, const float* __restrict__ b1,
    const __bf16* __restrict__ Wpq, signed char* __restrict__ P8,
    signed char* __restrict__ Q8, float* __restrict__ Psc,
    float* __restrict__ Qsc) {
  const int tid = threadIdx.x;
  const int w = tid >> 6, l = tid & 63;
  const int lg = l >> 4, lc = l & 15;
  const int base = blockIdx.x * 64;              // exact: 3125*64 = 200000
  const int rowA = base + w * 16 + lc;

  bf16x8 af[2];
#pragma unroll
  for (int kh = 0; kh < 2; ++kh) {
    const float4* zp = (const float4*)(Z + (size_t)rowA * HID + kh * 32 + lg * 8);
    const float4 f0 = zp[0], f1 = zp[1];
    bf16x8 a;
    a[0] = (__bf16)f0.x; a[1] = (__bf16)f0.y;
    a[2] = (__bf16)f0.z; a[3] = (__bf16)f0.w;
    a[4] = (__bf16)f1.x; a[5] = (__bf16)f1.y;
    a[6] = (__bf16)f1.z; a[7] = (__bf16)f1.w;
    af[kh] = a;
  }

  f32x4 acc[8];
#pragma unroll
  for (int t = 0; t < 8; ++t) acc[t] = (f32x4){0.f, 0.f, 0.f, 0.f};

#pragma unroll
  for (int t = 0; t < 8; ++t)
#pragma unroll
    for (int kh = 0; kh < 2; ++kh) {
      const bf16x8 bf =
          *(const bf16x8*)(Wpq + ((t * 2 + kh) * 4 + lg) * 128 + lc * 8);
      acc[t] = __builtin_amdgcn_mfma_f32_16x16x32_bf16(af[kh], bf, acc[t],
                                                       0, 0, 0);
    }

  // P values (t=0..3, +bias) and Q values (t=4..7), indexed [t][r]
  float pvv[4][4], qvv[4][4];
#pragma unroll
  for (int t = 0; t < 4; ++t) {
    const float bias = b1[t * 16 + lc];
#pragma unroll
    for (int r = 0; r < 4; ++r) {
      pvv[t][r] = acc[t][r] + bias;
      qvv[t][r] = acc[t + 4][r];
    }
  }

#pragma unroll
  for (int r = 0; r < 4; ++r) {
    float pm = fmaxf(fmaxf(fabsf(pvv[0][r]), fabsf(pvv[1][r])),
                     fmaxf(fabsf(pvv[2][r]), fabsf(pvv[3][r])));
    float qm = fmaxf(fmaxf(fabsf(qvv[0][r]), fabsf(qvv[1][r])),
                     fmaxf(fabsf(qvv[2][r]), fabsf(qvv[3][r])));
#pragma unroll
    for (int d = 1; d < 16; d <<= 1) {           // 16-lane row reduce
      pm = fmaxf(pm, __shfl_xor(pm, d, 64));
      qm = fmaxf(qm, __shfl_xor(qm, d, 64));
    }
    pm = fmaxf(pm, 1e-12f);
    qm = fmaxf(qm, 1e-12f);
    const float pinv = 127.f / pm, qinv = 127.f / qm;

    uint_t packP = 0, packQ = 0;
#pragma unroll
    for (int t = 0; t < 4; ++t) {
      const int qp = __float2int_rn(pvv[t][r] * pinv);
      const int qq = __float2int_rn(qvv[t][r] * qinv);
      packP |= (uint_t)(qp & 0xff) << (8 * t);
      packQ |= (uint_t)(qq & 0xff) << (8 * t);
    }
    const int grow = base + w * 16 + lg * 4 + r;
    *(uint_t*)(P8 + (size_t)grow * 64 + lc * 4) = packP;
    *(uint_t*)(Q8 + (size_t)grow * 64 + lc * 4) = packQ;
    if (lc == 0) {
      Psc[grow] = pm * (1.f / 127.f);
      Qsc[grow] = qm * (1.f / 127.f);
    }
  }
}

// ---------------------------------------------------------------------------
// Edge kernel v5 (int8): structure of r7's wave-cooperative kernel. Per
// edge: ONE dword/lane covers the full 256B P8 node block (lane l -> k=l>>4,
// bytes (l&15)*4..+3 = orig cols {t*16+lc}) + per-(row) scale; same for Q.
// Unique gather bytes halve vs bf16 -> FETCH ~372->~230MB.
// ---------------------------------------------------------------------------
__global__ __launch_bounds__(256) void edge_kernel5(
    const int* __restrict__ ei, const float* __restrict__ W2,
    const float* __restrict__ b2, const signed char* __restrict__ P8,
    const signed char* __restrict__ Q8, const float* __restrict__ Psc,
    const float* __restrict__ Qsc, float* __restrict__ ehf,
    float* __restrict__ ehall) {
  __shared__ float tile[4][KF][EPW + 1];           // pad: k-stride 65
  const int tid = threadIdx.x;
  const int w = tid >> 6;
  const int lane = tid & 63;
  const int lc = lane & 15, lk = lane >> 4;
  const int eb = blockIdx.x * 256 + w * EPW;       // this wave's 64 edges

  // lane's 4 W2 coefs for orig cols {t*16+lc}
  const float w2a = W2[lc],      w2b = W2[16 + lc];
  const float w2c = W2[32 + lc], w2d = W2[48 + lc];
  const float bias2 = b2[0];

  const int srcl = ei[eb + lane];                  // coalesced
  const int dstl = ei[E_EDGES + eb + lane];

  uint_t pv[4], qv[4];
  float ps[4], qs[4];
#pragma unroll
  for (int d = 0; d < 4; ++d) {
    const int s = __shfl(srcl, d, 64);             // readlane -> SGPR base
    const int t = __shfl(dstl, d, 64);
    pv[d] = *(const uint_t*)(P8 + (size_t)s * 256 + lane * 4);
    qv[d] = *(const uint_t*)(Q8 + (size_t)t * 256 + lane * 4);
    ps[d] = Psc[s * 4 + lk];
    qs[d] = Qsc[t * 4 + lk];
  }

#pragma unroll
  for (int i = 0; i < EPW; ++i) {
    const uint_t p = pv[i & 3], q = qv[i & 3];
    const float pss = ps[i & 3], qss = qs[i & 3];
    if (i + 4 < EPW) {                             // static under full unroll
      const int s = __shfl(srcl, i + 4, 64);
      const int t = __shfl(dstl, i + 4, 64);
      pv[i & 3] = *(const uint_t*)(P8 + (size_t)s * 256 + lane * 4);
      qv[i & 3] = *(const uint_t*)(Q8 + (size_t)t * 256 + lane * 4);
      ps[i & 3] = Psc[s * 4 + lk];
      qs[i & 3] = Qsc[t * 4 + lk];
    }
    // dequant + relu + partial dot (4 cols per lane)
    const float p0 = (float)((signed char)(p));
    const float p1 = (float)((signed char)(p >> 8));
    const float p2 = (float)((signed char)(p >> 16));
    const float p3 = (float)((signed char)(p >> 24));
    const float q0 = (float)((signed char)(q));
    const float q1 = (float)((signed char)(q >> 8));
    const float q2 = (float)((signed char)(q >> 16));
    const float q3 = (float)((signed char)(q >> 24));

    float s4 = fmaxf(fmaf(p0, pss, q0 * qss), 0.f) * w2a;
    s4 = fmaf(fmaxf(fmaf(p1, pss, q1 * qss), 0.f), w2b, s4);
    s4 = fmaf(fmaxf(fmaf(p2, pss, q2 * qss), 0.f), w2c, s4);
    s4 = fmaf(fmaxf(fmaf(p3, pss, q3 * qss), 0.f), w2d, s4);

    // sum the 16 lanes of this k-group
    s4 += __shfl_xor(s4, 1, 64);
    s4 += __shfl_xor(s4, 2, 64);
    s4 += __shfl_xor(s4, 4, 64);
    s4 += __shfl_xor(s4, 8, 64);
    if (lc == 0) tile[w][lk][i] = s4 + bias2;
  }
  __syncthreads();

  const float v0 = tile[w][0][lane];
  const float v1 = tile[w][1][lane];
  const float v2 = tile[w][2][lane];
  const float v3 = tile[w][3][lane];
  ehall[(size_t)0 * E_EDGES + eb + lane] = v0;     // coalesced per wave
  ehall[(size_t)1 * E_EDGES + eb + lane] = v1;
  ehall[(size_t)2 * E_EDGES + eb + lane] = v2;
  ehall[(size_t)3 * E_EDGES + eb + lane] = v3;
  ehf[eb + lane] = fmaxf(fmaxf(v0, v1), fmaxf(v2, v3));
}

// ---------------------------------------------------------------------------
extern "C" void kernel_launch(void* const* d_in, const int* in_sizes, int n_in,
                              void* d_out, int out_size, void* d_ws,
                              size_t ws_size, hipStream_t stream) {
  const float* x      = (const float*)d_in[0];
  const int*   ei     = (const int*)  d_in[1];
  const float* W_init = (const float*)d_in[2];
  const float* b_init = (const float*)d_in[3];
  const float* W1     = (const float*)d_in[4];
  const float* b1     = (const float*)d_in[5];
  const float* W2     = (const float*)d_in[6];
  const float* b2     = (const float*)d_in[7];
  float* out = (float*)d_out;

  // d_ws: P8 (12.8MB) | Q8 (12.8MB) | Psc (0.8MB) | Qsc (0.8MB) |
  //       Wz (64KB) | Wpq (16KB).  Total ~27.3MB << ws_size (>=102MB, r2).
  signed char* P8 = (signed char*)d_ws;
  signed char* Q8 = P8 + (size_t)NROWS * 64;
  float* Psc = (float*)(Q8 + (size_t)NROWS * 64);
  float* Qsc = Psc + NROWS;
  __bf16* Wz  = (__bf16*)(Qsc + NROWS);
  __bf16* Wpq = Wz + 32768;

  prep_kernel<<<41, 256, 0, stream>>>(W_init, W1, out + OFF_DISEN, Wz, Wpq);
  z_mfma_kernel2<<<(N_NODES + 63) / 64, 256, 0, stream>>>(
      x, b_init, Wz, out);
  pq_mfma_kernel2<<<NROWS / 64, 256, 0, stream>>>(
      out + OFF_Z, b1, Wpq, P8, Q8, Psc, Qsc);
  edge_kernel5<<<E_EDGES / 256, 256, 0, stream>>>(
      ei, W2, b2, P8, Q8, Psc, Qsc, out + OFF_EHF, out + OFF_EHALL);
}